// Round 12
// baseline (2173.712 us; speedup 1.0000x reference)
//
#include <hip/hip_runtime.h>

#define NQT 16384
#define NAT 512
#define EAQ 131072
#define EQQ 262144

typedef short short8 __attribute__((ext_vector_type(8)));
typedef float float4v __attribute__((ext_vector_type(4)));

__device__ __forceinline__ float silu_f(float x){ return x / (1.f + __expf(-x)); }

__device__ __forceinline__ short f2bf(float f){
  union { float f; unsigned u; } v; v.f = f;
  unsigned r = v.u + 0x7fff + ((v.u >> 16) & 1);
  return (short)(r >> 16);
}
__device__ __forceinline__ float bf2f(short s){
  union { unsigned u; float f; } v;
  v.u = ((unsigned)(unsigned short)s) << 16;
  return v.f;
}

// ---------------- counting sort by tgt (both edge sets) ----------------
__global__ __launch_bounds__(256) void k_hist2(
    const int* __restrict__ ta, const int* __restrict__ tq,
    int* __restrict__ ha, int* __restrict__ hq)
{
  int i = blockIdx.x*256 + threadIdx.x;
  atomicAdd(&hq[tq[i]], 1);
  if (i < EAQ) atomicAdd(&ha[ta[i]], 1);
}

__global__ __launch_bounds__(256) void k_scan2(int* __restrict__ ha, int* __restrict__ hq)
{
  int* hist = (blockIdx.x == 0) ? ha : hq;
  __shared__ int part[256];
  int t = threadIdx.x;
  int base = t * 64;
  int s = 0;
  for (int i = 0; i < 64; i++) s += hist[base + i];
  part[t] = s;
  __syncthreads();
  for (int off = 1; off < 256; off <<= 1){
    int v = (t >= off) ? part[t - off] : 0;
    __syncthreads();
    part[t] += v;
    __syncthreads();
  }
  int run = (t == 0) ? 0 : part[t-1];
  for (int i = 0; i < 64; i++){
    int h = hist[base + i];
    hist[base + i] = run;
    run += h;
  }
}

__global__ __launch_bounds__(256) void k_place2(
    const int* __restrict__ sa, const int* __restrict__ ta,
    const int* __restrict__ sq, const int* __restrict__ tq,
    int* __restrict__ ca, int* __restrict__ cq,
    int2* __restrict__ da, int2* __restrict__ dq)
{
  int i = blockIdx.x*256 + threadIdx.x;
  { int tg = tq[i]; int pos = atomicAdd(&cq[tg], 1); dq[pos] = make_int2(sq[i], tg); }
  if (i < EAQ){ int tg = ta[i]; int pos = atomicAdd(&ca[tg], 1); da[pos] = make_int2(sa[i], tg); }
}

// ---------------- weight packer (all jobs, one launch) ----------------
// layout: [ntiles][ksteps][64 lanes][8]; lane gives B[k=kk*32+(lane>>4)*8+j][n=nt*16+(lane&15)]
__device__ __forceinline__ void pack_one(
    const float* __restrict__ W, short* __restrict__ out,
    int rows, int cols, int ksteps, int ntiles, int idx, int mode)
{
  int l8   = idx & 7;
  int lane = (idx >> 3) & 63;
  int kk   = (idx >> 9) % ksteps;
  int nt   = ((idx >> 9) / ksteps) % ntiles;
  int j    = idx / (512 * ksteps * ntiles);
  int k = kk*32 + (lane >> 4)*8 + l8;
  if (mode == 1) k += (k >= 256);
  else if (mode == 2) k = (k < 128) ? k + 128 : k + 129;   // [h_tgt | temb] rows of W1
  int n = nt*16 + (lane & 15);
  out[idx] = f2bf(W[(size_t)j*rows*cols + (size_t)k*cols + n]);
}

__global__ __launch_bounds__(256) void k_packall(
    const float* __restrict__ mW1, const float* __restrict__ mW2,
    const float* __restrict__ cW1, const float* __restrict__ nW1,
    const float* __restrict__ nW2, const float* __restrict__ tW1,
    const float* __restrict__ tW2,
    short* W1ap, short* W1bcp, short* W2p, short* W3p,
    short* nW1p, short* nW2p, short* tW1p, short* tW2p)
{
  int b = blockIdx.x, t = threadIdx.x;
  if (b < 1024){ pack_one(mW1, W1ap, 385,256,4,16, b*256+t, 0); return; } b -= 1024;
  if (b < 2048){ pack_one(mW1, W1bcp,385,256,8,16, b*256+t, 2); return; } b -= 2048;
  if (b < 1024){ pack_one(mW2, W2p,  256,128,8, 8, b*256+t, 0); return; } b -= 1024;
  if (b <  256){ pack_one(cW1, W3p,  128, 64,4, 4, b*256+t, 0); return; } b -=  256;
  if (b < 1024){ pack_one(nW1, nW1p, 256,128,8, 8, b*256+t, 0); return; } b -= 1024;
  if (b <  512){ pack_one(nW2, nW2p, 128,128,4, 8, b*256+t, 0); return; } b -=  512;
  if (b <  256){ pack_one(tW1, tW1p, 128,512,4,32, b*256+t, 0); return; } b -=  256;
  pack_one(tW2, tW2p, 512,128,16,8, b*256+t, 0);
}

// ---------------- initial operand production: Ptgt_0 (f32) + all 4 AQ Psrc (bf16) ----------------
__global__ __launch_bounds__(256) void k_pre0(
    const float* __restrict__ hA, const float* __restrict__ temb,
    const float* __restrict__ mb1_0, const short* __restrict__ W1bcp0,
    const float* __restrict__ h_atom, const short* __restrict__ W1ap_base,
    float* __restrict__ Ptgt, short* __restrict__ psrc_aq)
{
  int t = threadIdx.x;
  int lane = t & 63, w = t >> 6;
  int mrow = lane & 15, quad = lane >> 4;
  int b = blockIdx.x;

  if (b < NQT/64){
    int m0 = b*64 + w*16;
    short8 areg[8];
    #pragma unroll
    for (int kk = 0; kk < 8; kk++){
      int k = kk*32 + quad*8;
      const float* bp = (kk >= 4) ? (temb + (size_t)(m0+mrow)*128 + (k - 128))
                                  : (hA   + (size_t)(m0+mrow)*128 + k);
      float4 f0 = *(const float4*)(bp);
      float4 f1 = *(const float4*)(bp + 4);
      short8 s;
      s[0]=f2bf(f0.x); s[1]=f2bf(f0.y); s[2]=f2bf(f0.z); s[3]=f2bf(f0.w);
      s[4]=f2bf(f1.x); s[5]=f2bf(f1.y); s[6]=f2bf(f1.z); s[7]=f2bf(f1.w);
      areg[kk] = s;
    }
    #pragma unroll
    for (int nt = 0; nt < 16; nt++){
      float4v acc = {0.f,0.f,0.f,0.f};
      const short8* Bb = (const short8*)(W1bcp0 + ((size_t)nt*8)*512 + lane*8);
      #pragma unroll
      for (int kk = 0; kk < 8; kk++)
        acc = __builtin_amdgcn_mfma_f32_16x16x32_bf16(areg[kk], Bb[kk*64], acc, 0, 0, 0);
      float bv = mb1_0[nt*16 + mrow];
      #pragma unroll
      for (int r = 0; r < 4; r++)
        Ptgt[(size_t)(m0 + quad*4 + r)*256 + nt*16 + mrow] = acc[r] + bv;
    }
  } else {
    int bb = b - NQT/64;
    int idx = bb >> 3;                    // AQ layer slot 0..3 -> layer j=2*idx
    int m0 = (bb & 7)*64 + w*16;
    const short* Wp = W1ap_base + (size_t)(2*idx)*32768;
    short8 areg[4];
    #pragma unroll
    for (int kk = 0; kk < 4; kk++){
      const float* bp = h_atom + (size_t)(m0+mrow)*128 + kk*32 + quad*8;
      float4 f0 = *(const float4*)(bp);
      float4 f1 = *(const float4*)(bp + 4);
      short8 s;
      s[0]=f2bf(f0.x); s[1]=f2bf(f0.y); s[2]=f2bf(f0.z); s[3]=f2bf(f0.w);
      s[4]=f2bf(f1.x); s[5]=f2bf(f1.y); s[6]=f2bf(f1.z); s[7]=f2bf(f1.w);
      areg[kk] = s;
    }
    #pragma unroll
    for (int nt = 0; nt < 16; nt++){
      float4v acc = {0.f,0.f,0.f,0.f};
      const short8* Bb = (const short8*)(Wp + ((size_t)nt*4)*512 + lane*8);
      #pragma unroll
      for (int kk = 0; kk < 4; kk++)
        acc = __builtin_amdgcn_mfma_f32_16x16x32_bf16(areg[kk], Bb[kk*64], acc, 0, 0, 0);
      #pragma unroll
      for (int r = 0; r < 4; r++)
        psrc_aq[(size_t)idx*131072 + (size_t)(m0 + quad*4 + r)*256 + nt*16 + mrow] = f2bf(acc[r]);
    }
  }
}

// ---------------- h_atom ----------------
__global__ __launch_bounds__(128) void k_hatom(
    const float* __restrict__ feat, const float* __restrict__ W,
    const float* __restrict__ b, float* __restrict__ out)
{
  __shared__ float sf[256];
  int n = blockIdx.x, t = threadIdx.x;
  sf[t]       = feat[n*256 + t];
  sf[t + 128] = feat[n*256 + 128 + t];
  __syncthreads();
  float acc = b[t];
  for (int k = 0; k < 256; k++) acc += sf[k] * W[k*128 + t];
  out[n*128 + t] = acc;
}

// ---------------- t_emb (MFMA) ----------------
__global__ __launch_bounds__(256) void k_temb(
    const float* __restrict__ tq,
    const short* __restrict__ W1p, const float* __restrict__ b1,
    const short* __restrict__ W2p, const float* __restrict__ b2,
    float* __restrict__ temb)
{
  __shared__ __align__(16) short A[32*136];
  __shared__ __align__(16) short B[32*528];
  int t = threadIdx.x;
  int n0 = blockIdx.x * 32;

  {
    int row = t >> 3, l = t & 7;
    float tv = tq[n0 + row];
    short* o = A + row*136;
    #pragma unroll
    for (int i = 0; i < 16; i++){
      int k = l*16 + i;
      int h = k & 63;
      float freq = __expf(-9.210340371976184f * (float)h * (1.f/63.f));
      float a = tv * freq;
      float v = (k < 64) ? __sinf(a) : __cosf(a);
      o[k] = f2bf(v);
    }
  }
  __syncthreads();

  int lane = t & 63, w = t >> 6;
  int mrow = lane & 15, quad = lane >> 4;

  for (int nti = 0; nti < 8; nti++){
    int nt = w*8 + nti;
    #pragma unroll
    for (int mt = 0; mt < 2; mt++){
      float4v acc = {0.f,0.f,0.f,0.f};
      const short8* Ab = (const short8*)(A + (mt*16 + mrow)*136 + quad*8);
      const short8* Bb = (const short8*)(W1p + (size_t)nt*4*512 + lane*8);
      #pragma unroll
      for (int kk = 0; kk < 4; kk++)
        acc = __builtin_amdgcn_mfma_f32_16x16x32_bf16(Ab[kk*4], Bb[kk*64], acc, 0, 0, 0);
      int n = nt*16 + mrow;
      float b1n = b1[n];
      #pragma unroll
      for (int r = 0; r < 4; r++)
        B[(mt*16 + quad*4 + r)*528 + n] = f2bf(silu_f(acc[r] + b1n));
    }
  }
  __syncthreads();

  #pragma unroll
  for (int nti = 0; nti < 2; nti++){
    int nt = w*2 + nti;
    #pragma unroll
    for (int mt = 0; mt < 2; mt++){
      float4v acc = {0.f,0.f,0.f,0.f};
      const short8* Ab = (const short8*)(B + (mt*16 + mrow)*528 + quad*8);
      const short8* Bb = (const short8*)(W2p + (size_t)nt*16*512 + lane*8);
      #pragma unroll
      for (int kk = 0; kk < 16; kk++)
        acc = __builtin_amdgcn_mfma_f32_16x16x32_bf16(Ab[kk*4], Bb[kk*64], acc, 0, 0, 0);
      int n = nt*16 + mrow;
      float b2n = b2[n];
      #pragma unroll
      for (int r = 0; r < 4; r++)
        temb[(size_t)(n0 + mt*16 + quad*4 + r)*128 + n] = acc[r] + b2n;
    }
  }
}

// ---------------- h init: 16 nodes / 256-thread block ----------------
__global__ __launch_bounds__(256) void k_hinit(
    const float* __restrict__ x_t, const float* __restrict__ atom_pos,
    const float* __restrict__ W1, const float* __restrict__ b1,
    const float* __restrict__ W2, const float* __restrict__ b2,
    float* __restrict__ h)
{
  __shared__ float sh[16*128];
  int t = threadIdx.x;
  int n0 = blockIdx.x * 16;
  int r = t >> 4, l = t & 15;
  int n = n0 + r;

  float qx = x_t[n*3], qy = x_t[n*3+1], qz = x_t[n*3+2];
  int batch = n >> 11;
  float part = 0.f;
  #pragma unroll
  for (int i = 0; i < 4; i++){
    int a = batch*64 + l*4 + i;
    float dx = qx - atom_pos[a*3], dy = qy - atom_pos[a*3+1], dz = qz - atom_pos[a*3+2];
    part += dx*dx + dy*dy + dz*dz;
  }
  part += __shfl_xor(part, 1);
  part += __shfl_xor(part, 2);
  part += __shfl_xor(part, 4);
  part += __shfl_xor(part, 8);
  float ld = log1pf(sqrtf(part * (1.f/64.f)) * 0.125f);

  #pragma unroll
  for (int cc = 0; cc < 8; cc++){
    int c = l*8 + cc;
    sh[r*128 + c] = silu_f(ld * W1[c] + b1[c]);
  }
  __syncthreads();

  const float* shr = sh + r*128;
  #pragma unroll
  for (int cc = 0; cc < 8; cc++){
    int c = l*8 + cc;
    float acc = b2[c];
    for (int k = 0; k < 128; k++) acc += shr[k] * W2[k*128 + c];
    h[(size_t)n*128 + c] = acc;
  }
}

// ---------------- EGNN edge kernel: 256 threads / 32 edges (R10 shape, f32 Ptgt) ----------------
__global__ __launch_bounds__(256) void k_edge(
    const short* __restrict__ Psrc, const float* __restrict__ Ptgt,
    const float* __restrict__ pos_src, const float* __restrict__ pos_tgt,
    const int2* __restrict__ sdesc,
    const float* __restrict__ w1sq,
    const short* __restrict__ W2p, const float* __restrict__ b2,
    const short* __restrict__ W3p, const float* __restrict__ b3,
    const float* __restrict__ W4,  const float* __restrict__ b4,
    float* __restrict__ agg, float* __restrict__ vel)
{
  __shared__ __align__(16) short A2[32*264];   // pre1 bf16 str264; later msgf f32 str132; later h3 f32 str68
  __shared__ __align__(16) short A3[32*136];   // msg bf16 str 136
  __shared__ float rel_s[32*3];
  __shared__ int   tgt_s[32];
  float* msgf = (float*)A2;
  float* h3   = (float*)A2;

  int t = threadIdx.x;
  int e0 = blockIdx.x * 32;

  // ---- stage: pre1 = Psrc[src] + Ptgt[tgt](f32, b1 folded) + sq*w1sq -> silu -> A2 ----
  {
    int e = t >> 3, l = t & 7;
    int2 d = sdesc[e0 + e];
    int src = d.x, tgt = d.y;
    float rx = pos_tgt[tgt*3+0] - pos_src[src*3+0];
    float ry = pos_tgt[tgt*3+1] - pos_src[src*3+1];
    float rz = pos_tgt[tgt*3+2] - pos_src[src*3+2];
    float sqv = rx*rx + ry*ry + rz*rz;
    if (l == 0){
      rel_s[e*3+0]=rx; rel_s[e*3+1]=ry; rel_s[e*3+2]=rz;
      tgt_s[e] = tgt;
    }
    const short8*  ps = (const short8*)(Psrc + (size_t)src*256);
    const float4*  pt = (const float4*)(Ptgt + (size_t)tgt*256);
    #pragma unroll
    for (int c = 0; c < 4; c++){
      int ci = c*8 + l;
      int n0 = ci*8;
      short8 a = ps[ci];
      float4 b0 = pt[ci*2], b1v = pt[ci*2+1];
      float4 w0 = *(const float4*)(w1sq + n0);
      float4 w1 = *(const float4*)(w1sq + n0 + 4);
      short8 r;
      r[0] = f2bf(silu_f(bf2f(a[0]) + b0.x  + sqv*w0.x));
      r[1] = f2bf(silu_f(bf2f(a[1]) + b0.y  + sqv*w0.y));
      r[2] = f2bf(silu_f(bf2f(a[2]) + b0.z  + sqv*w0.z));
      r[3] = f2bf(silu_f(bf2f(a[3]) + b0.w  + sqv*w0.w));
      r[4] = f2bf(silu_f(bf2f(a[4]) + b1v.x + sqv*w1.x));
      r[5] = f2bf(silu_f(bf2f(a[5]) + b1v.y + sqv*w1.y));
      r[6] = f2bf(silu_f(bf2f(a[6]) + b1v.z + sqv*w1.z));
      r[7] = f2bf(silu_f(bf2f(a[7]) + b1v.w + sqv*w1.w));
      *(short8*)(A2 + e*264 + n0) = r;
    }
  }
  __syncthreads();

  int lane = t & 63, w = t >> 6;
  int mrow = lane & 15, quad = lane >> 4;

  // ---- GEMM2: hoist A-fragments to registers ONCE, reuse across both n-tiles ----
  short8 afr[2][8];
  #pragma unroll
  for (int mt = 0; mt < 2; mt++){
    const short8* Ab = (const short8*)(A2 + (mt*16 + mrow)*264 + quad*8);
    #pragma unroll
    for (int kk = 0; kk < 8; kk++)
      afr[mt][kk] = Ab[kk*4];
  }
  float4v acc2[2][2];
  #pragma unroll
  for (int nti = 0; nti < 2; nti++){
    int nt = w*2 + nti;
    #pragma unroll
    for (int mt = 0; mt < 2; mt++){
      float4v acc = {0.f,0.f,0.f,0.f};
      const short8* Bb = (const short8*)(W2p + (size_t)nt*8*512 + lane*8);
      #pragma unroll
      for (int kk = 0; kk < 8; kk++)
        acc = __builtin_amdgcn_mfma_f32_16x16x32_bf16(afr[mt][kk], Bb[kk*64], acc, 0, 0, 0);
      acc2[nti][mt] = acc;
    }
  }
  __syncthreads();   // A2 reads done — region becomes msgf

  // ---- epilogue: silu -> msgf (f32) + A3 (bf16) ----
  #pragma unroll
  for (int nti = 0; nti < 2; nti++){
    int n = (w*2 + nti)*16 + mrow;
    float b2n = b2[n];
    #pragma unroll
    for (int mt = 0; mt < 2; mt++){
      #pragma unroll
      for (int r = 0; r < 4; r++){
        int e = mt*16 + quad*4 + r;
        float v = silu_f(acc2[nti][mt][r] + b2n);
        msgf[e*132 + n] = v;
        A3[e*136 + n]   = f2bf(v);
      }
    }
  }
  __syncthreads();

  // ---- GEMM3 MFMAs first (regs only, overlaps reduce latency) ----
  float4v acc3[2];
  {
    int nt = w;
    #pragma unroll
    for (int mt = 0; mt < 2; mt++){
      float4v acc = {0.f,0.f,0.f,0.f};
      const short8* Ab = (const short8*)(A3 + (mt*16 + mrow)*136 + quad*8);
      const short8* Bb = (const short8*)(W3p + (size_t)nt*4*512 + lane*8);
      #pragma unroll
      for (int kk = 0; kk < 4; kk++)
        acc = __builtin_amdgcn_mfma_f32_16x16x32_bf16(Ab[kk*4], Bb[kk*64], acc, 0, 0, 0);
      acc3[mt] = acc;
    }
  }

  // ---- segmented agg reduction (sorted by tgt), f32, 2 groups of 16 ----
  {
    int c = t & 127, hh = t >> 7;
    int eb = hh*16;
    float run = 0.f;
    int cur = tgt_s[eb];
    for (int e = eb; e < eb + 16; e++){
      int tg = tgt_s[e];
      if (tg != cur){
        atomicAdd(&agg[(size_t)cur*128 + c], run);
        run = 0.f; cur = tg;
      }
      run += msgf[e*132 + c];
    }
    atomicAdd(&agg[(size_t)cur*128 + c], run);
  }
  __syncthreads();   // msgf reads done — region becomes h3

  // ---- write h3 ----
  {
    int n = w*16 + mrow;
    float b3n = b3[n];
    #pragma unroll
    for (int mt = 0; mt < 2; mt++){
      #pragma unroll
      for (int r = 0; r < 4; r++){
        int e = mt*16 + quad*4 + r;
        h3[e*68 + n] = silu_f(acc3[mt][r] + b3n);
      }
    }
  }
  __syncthreads();

  // ---- GEMM4 (f32 dot-64) + tanh + vel scatter ----
  {
    int e = t >> 3, l = t & 7;
    float p = 0.f;
    #pragma unroll
    for (int i = 0; i < 8; i++){
      int k = l + 8*i;
      p += h3[e*68 + k] * W4[k];
    }
    p += __shfl_xor(p, 1);
    p += __shfl_xor(p, 2);
    p += __shfl_xor(p, 4);
    if (l == 0){
      float wv = tanhf(p + b4[0]);
      int tg = tgt_s[e];
      atomicAdd(&vel[tg*3+0], wv*rel_s[e*3+0]);
      atomicAdd(&vel[tg*3+1], wv*rel_s[e*3+1]);
      atomicAdd(&vel[tg*3+2], wv*rel_s[e*3+2]);
    }
  }
}

// ---------------- node update (MFMA) + fused next-layer operand production ----------------
__global__ __launch_bounds__(256) void k_node(
    const float* __restrict__ h, float* __restrict__ agg,
    const short* __restrict__ W1p, const float* __restrict__ b1,
    const short* __restrict__ W2p, const float* __restrict__ b2,
    const float* __restrict__ g, const float* __restrict__ bb_,
    float* __restrict__ h_out,
    int produce,                                   // 0 none, 1 Ptgt, 2 Ptgt+Psrc
    const float* __restrict__ temb,
    const short* __restrict__ W1bcN, const float* __restrict__ mb1N,
    const short* __restrict__ W1aN,
    float* __restrict__ Ptgt, short* __restrict__ PsrcQ)
{
  __shared__ __align__(16) short A[32*264];   // u bf16 str264; later r f32 str132
  __shared__ __align__(16) short B[32*136];   // hid bf16 str136
  __shared__ __align__(16) short S[32*264];   // [h_new | temb] bf16 str264 (production)
  float* r = (float*)A;
  int t = threadIdx.x;
  int n0 = blockIdx.x * 32;

  { // stage u = [h|agg] bf16, zero agg; stage temb -> S cols 128..255
    int row = t >> 3, l = t & 7;
    const float4* hr = (const float4*)(h + (size_t)(n0+row)*128);
    float4*       ar = (float4*)(agg + (size_t)(n0+row)*128);
    const float4* te = (const float4*)(temb + (size_t)(n0+row)*128);
    short* o = A + row*264;
    short* so = S + row*264 + 128;
    float4 z = make_float4(0.f,0.f,0.f,0.f);
    #pragma unroll
    for (int i = 0; i < 4; i++){
      int k4 = l + 8*i;
      float4 a = hr[k4];
      o[k4*4+0]=f2bf(a.x); o[k4*4+1]=f2bf(a.y); o[k4*4+2]=f2bf(a.z); o[k4*4+3]=f2bf(a.w);
      float4 b = ar[k4];
      o[128 + k4*4+0]=f2bf(b.x); o[128 + k4*4+1]=f2bf(b.y);
      o[128 + k4*4+2]=f2bf(b.z); o[128 + k4*4+3]=f2bf(b.w);
      ar[k4] = z;
      if (produce){
        float4 c = te[k4];
        so[k4*4+0]=f2bf(c.x); so[k4*4+1]=f2bf(c.y);
        so[k4*4+2]=f2bf(c.z); so[k4*4+3]=f2bf(c.w);
      }
    }
  }
  __syncthreads();

  int lane = t & 63, w = t >> 6;
  int mrow = lane & 15, quad = lane >> 4;

  // GEMM_A: (32x256)@(256x128)
  float4v accA[2][2];
  #pragma unroll
  for (int nti = 0; nti < 2; nti++){
    int nt = w*2 + nti;
    #pragma unroll
    for (int mt = 0; mt < 2; mt++){
      float4v acc = {0.f,0.f,0.f,0.f};
      const short8* Ab = (const short8*)(A + (mt*16 + mrow)*264 + quad*8);
      const short8* Bb = (const short8*)(W1p + (size_t)nt*8*512 + lane*8);
      #pragma unroll
      for (int kk = 0; kk < 8; kk++)
        acc = __builtin_amdgcn_mfma_f32_16x16x32_bf16(Ab[kk*4], Bb[kk*64], acc, 0, 0, 0);
      accA[nti][mt] = acc;
    }
  }
  __syncthreads();

  #pragma unroll
  for (int nti = 0; nti < 2; nti++){
    int n = (w*2 + nti)*16 + mrow;
    float b1n = b1[n];
    #pragma unroll
    for (int mt = 0; mt < 2; mt++){
      #pragma unroll
      for (int rr = 0; rr < 4; rr++){
        int e = mt*16 + quad*4 + rr;
        B[e*136 + n] = f2bf(silu_f(accA[nti][mt][rr] + b1n));
      }
    }
  }
  __syncthreads();

  // GEMM_B: (32x128)@(128x128) -> residual -> r
  #pragma unroll
  for (int nti = 0; nti < 2; nti++){
    int nt = w*2 + nti;
    #pragma unroll
    for (int mt = 0; mt < 2; mt++){
      float4v acc = {0.f,0.f,0.f,0.f};
      const short8* Ab = (const short8*)(B + (mt*16 + mrow)*136 + quad*8);
      const short8* Bb = (const short8*)(W2p + (size_t)nt*4*512 + lane*8);
      #pragma unroll
      for (int kk = 0; kk < 4; kk++)
        acc = __builtin_amdgcn_mfma_f32_16x16x32_bf16(Ab[kk*4], Bb[kk*64], acc, 0, 0, 0);
      int n = nt*16 + mrow;
      float b2n = b2[n];
      #pragma unroll
      for (int rr = 0; rr < 4; rr++){
        int e = mt*16 + quad*4 + rr;
        r[e*132 + n] = h[(size_t)(n0+e)*128 + n] + acc[rr] + b2n;
      }
    }
  }
  __syncthreads();

  // LayerNorm -> h_out global + S cols 0..127 (bf16)
  {
    int lane2 = t & 63, wid = t >> 6;
    #pragma unroll
    for (int nn = 0; nn < 8; nn++){
      int row = wid*8 + nn;
      float a = r[row*132 + lane2], bv = r[row*132 + lane2 + 64];
      float s = a + bv, ss = a*a + bv*bv;
      #pragma unroll
      for (int off = 1; off < 64; off <<= 1){
        s  += __shfl_xor(s, off);
        ss += __shfl_xor(ss, off);
      }
      float mean = s * (1.f/128.f);
      float var  = ss * (1.f/128.f) - mean*mean;
      float rstd = rsqrtf(var + 1e-5f);
      float v0 = (a  - mean)*rstd*g[lane2]      + bb_[lane2];
      float v1 = (bv - mean)*rstd*g[lane2 + 64] + bb_[lane2 + 64];
      float* ho = h_out + (size_t)(n0+row)*128;
      ho[lane2]      = v0;
      ho[lane2 + 64] = v1;
      S[row*264 + lane2]      = f2bf(v0);
      S[row*264 + lane2 + 64] = f2bf(v1);
    }
  }
  if (!produce) return;
  __syncthreads();

  // ---- produce Ptgt_{j+1} (f32) = [h_new|temb] @ W1bcN + mb1N ----
  #pragma unroll
  for (int nti = 0; nti < 4; nti++){
    int nt = w*4 + nti;
    #pragma unroll
    for (int mt = 0; mt < 2; mt++){
      float4v acc = {0.f,0.f,0.f,0.f};
      const short8* Ab = (const short8*)(S + (mt*16 + mrow)*264 + quad*8);
      const short8* Bb = (const short8*)(W1bcN + (size_t)nt*8*512 + lane*8);
      #pragma unroll
      for (int kk = 0; kk < 8; kk++)
        acc = __builtin_amdgcn_mfma_f32_16x16x32_bf16(Ab[kk*4], Bb[kk*64], acc, 0, 0, 0);
      int n = nt*16 + mrow;
      float bv = mb1N[n];
      #pragma unroll
      for (int rr = 0; rr < 4; rr++)
        Ptgt[(size_t)(n0 + mt*16 + quad*4 + rr)*256 + n] = acc[rr] + bv;
    }
  }

  // ---- produce Psrc_{j+1} = h_new @ W1aN (QQ next layer only) ----
  if (produce == 2){
    #pragma unroll
    for (int nti = 0; nti < 4; nti++){
      int nt = w*4 + nti;
      #pragma unroll
      for (int mt = 0; mt < 2; mt++){
        float4v acc = {0.f,0.f,0.f,0.f};
        const short8* Ab = (const short8*)(S + (mt*16 + mrow)*264 + quad*8);
        const short8* Bb = (const short8*)(W1aN + (size_t)nt*4*512 + lane*8);
        #pragma unroll
        for (int kk = 0; kk < 4; kk++)
          acc = __builtin_amdgcn_mfma_f32_16x16x32_bf16(Ab[kk*4], Bb[kk*64], acc, 0, 0, 0);
        int n = nt*16 + mrow;
        #pragma unroll
        for (int rr = 0; rr < 4; rr++)
          PsrcQ[(size_t)(n0 + mt*16 + quad*4 + rr)*256 + n] = f2bf(acc[rr]);
      }
    }
  }
}

// ---------------- output: 16 nodes / 256-thread block ----------------
__global__ __launch_bounds__(256) void k_out(
    const float* __restrict__ h, const float* __restrict__ vel,
    const float* __restrict__ W1, const float* __restrict__ b1,
    const float* __restrict__ W2, const float* __restrict__ b2,
    float* __restrict__ out)
{
  __shared__ float sh[16*128];
  __shared__ float sc[16];
  int t = threadIdx.x;
  int n0 = blockIdx.x * 16;
  int r = t >> 4, l = t & 15;

  { // stage h rows
    const float4* src = (const float4*)(h + (size_t)(n0 + r)*128);
    float4* dst = (float4*)(sh + r*128);
    dst[l*2]   = src[l*2];
    dst[l*2+1] = src[l*2+1];
  }
  __syncthreads();

  const float* hr = sh + r*128;
  float part = 0.f;
  #pragma unroll
  for (int cc = 0; cc < 8; cc++){
    int c = l*8 + cc;
    float acc = b1[c];
    for (int k = 0; k < 128; k++) acc += hr[k] * W1[k*128 + c];
    part += silu_f(acc) * W2[c];
  }
  part += __shfl_xor(part, 1);
  part += __shfl_xor(part, 2);
  part += __shfl_xor(part, 4);
  part += __shfl_xor(part, 8);
  if (l == 0) sc[r] = part + b2[0];
  __syncthreads();

  if (t < 48){
    int rr = t / 3, d = t % 3;
    out[(size_t)(n0+rr)*3 + d] = vel[(size_t)(n0+rr)*3 + d] * sc[rr];
  }
}

extern "C" void kernel_launch(void* const* d_in, const int* in_sizes, int n_in,
                              void* d_out, int out_size, void* d_ws, size_t ws_size,
                              hipStream_t stream)
{
  const float* x_t       = (const float*)d_in[0];
  const float* t_query   = (const float*)d_in[1];
  const float* atom_pos  = (const float*)d_in[2];
  const float* atom_feat = (const float*)d_in[3];
  const int*   e_aq_s = (const int*)d_in[4];
  const int*   e_aq_t = (const int*)d_in[5];
  const int*   e_qq_s = (const int*)d_in[6];
  const int*   e_qq_t = (const int*)d_in[7];
  const float* apW  = (const float*)d_in[8];
  const float* apb  = (const float*)d_in[9];
  const float* tW1  = (const float*)d_in[10];
  const float* tb1  = (const float*)d_in[11];
  const float* tW2  = (const float*)d_in[12];
  const float* tb2  = (const float*)d_in[13];
  const float* qiW1 = (const float*)d_in[14];
  const float* qib1 = (const float*)d_in[15];
  const float* qiW2 = (const float*)d_in[16];
  const float* qib2 = (const float*)d_in[17];
  const float* mW1  = (const float*)d_in[18];
  const float* mb1  = (const float*)d_in[19];
  const float* mW2  = (const float*)d_in[20];
  const float* mb2  = (const float*)d_in[21];
  const float* cW1  = (const float*)d_in[22];
  const float* cb1  = (const float*)d_in[23];
  const float* cW2  = (const float*)d_in[24];
  const float* cb2  = (const float*)d_in[25];
  const float* nW1  = (const float*)d_in[26];
  const float* nb1  = (const float*)d_in[27];
  const float* nW2  = (const float*)d_in[28];
  const float* nb2  = (const float*)d_in[29];
  const float* lng  = (const float*)d_in[30];
  const float* lnb  = (const float*)d_in[31];
  const float* voW1 = (const float*)d_in[32];
  const float* vob1 = (const float*)d_in[33];
  const float* voW2 = (const float*)d_in[34];
  const float* vob2 = (const float*)d_in[35];
  float* out = (float*)d_out;

  float* ws     = (float*)d_ws;
  float* h_atom = ws;                        // 65536
  float* temb   = h_atom + 65536;            // 2097152
  float* hA     = temb + 2097152;
  float* hB     = hA + 2097152;
  float* agg    = hB + 2097152;              // contiguous with vel
  float* vel    = agg + 2097152;             // 49152
  short* W1ap   = (short*)(vel + 49152);     // 262144
  short* W1bcp  = W1ap + 262144;             // 524288
  short* W2p    = W1bcp + 524288;            // 262144
  short* W3p    = W2p + 262144;              // 65536
  short* nW1p   = W3p + 65536;               // 262144
  short* nW2p   = nW1p + 262144;             // 131072
  short* tW1p   = nW2p + 131072;             // 65536
  short* tW2p   = tW1p + 65536;              // 65536
  short* PsrcQ  = tW2p + 65536;              // 4194304 shorts
  short* psrc_aq= PsrcQ + 4194304;           // 524288 shorts
  float* PtgtF  = (float*)(psrc_aq + 524288);// 4194304 floats (f32 Ptgt)
  int*   hist_a = (int*)(PtgtF + 4194304);   // 16384 (contiguous with hist_q)
  int*   hist_q = hist_a + 16384;            // 16384
  int2*  desc_a = (int2*)(hist_q + 16384);   // EAQ
  int2*  desc_q = desc_a + EAQ;              // EQQ

  // ---- sort both edge sets ----
  hipMemsetAsync(hist_a, 0, 2*16384*sizeof(int), stream);
  k_hist2<<<EQQ/256, 256, 0, stream>>>(e_aq_t, e_qq_t, hist_a, hist_q);
  k_scan2<<<2, 256, 0, stream>>>(hist_a, hist_q);
  k_place2<<<EQQ/256, 256, 0, stream>>>(e_aq_s, e_aq_t, e_qq_s, e_qq_t,
                                        hist_a, hist_q, desc_a, desc_q);

  // ---- all weight packing in one launch ----
  k_packall<<<6400, 256, 0, stream>>>(mW1, mW2, cW1, nW1, nW2, tW1, tW2,
      W1ap, W1bcp, W2p, W3p, nW1p, nW2p, tW1p, tW2p);

  // zero agg + vel (contiguous)
  hipMemsetAsync(agg, 0, (size_t)(NQT*128 + NQT*3)*sizeof(float), stream);
  k_hatom<<<NAT, 128, 0, stream>>>(atom_feat, apW, apb, h_atom);
  k_temb<<<NQT/32, 256, 0, stream>>>(t_query, tW1p, tb1, tW2p, tb2, temb);
  k_hinit<<<NQT/16, 256, 0, stream>>>(x_t, atom_pos, qiW1, qib1, qiW2, qib2, hA);

  // initial operands: Ptgt (f32) for layer 0 + Psrc for all 4 AQ layers
  k_pre0<<<NQT/64 + 32, 256, 0, stream>>>(hA, temb, mb1, W1bcp, h_atom, W1ap,
                                          PtgtF, psrc_aq);

  float* hc = hA; float* hn = hB;
  for (int j = 0; j < 8; j++){
    int half = j & 1;                       // 0 = AQ, 1 = QQ
    const int2* dsc = half ? desc_q : desc_a;
    int E = half ? EQQ : EAQ;
    const short* psrc = half ? PsrcQ : (psrc_aq + (size_t)(j >> 1)*131072);

    k_edge<<<E/32, 256, 0, stream>>>(psrc, PtgtF,
        half ? x_t : atom_pos, x_t, dsc,
        mW1 + (size_t)j*385*256 + 65536,
        W2p + (size_t)j*32768, mb2 + (size_t)j*128,
        W3p + (size_t)j*8192,  cb1 + (size_t)j*64,
        cW2 + (size_t)j*64,    cb2 + (size_t)j,
        agg, vel);

    int jn = (j < 7) ? (j + 1) : 7;         // next-layer weights (dummy when produce=0)
    int produce = (j == 7) ? 0 : ((half == 0) ? 2 : 1);
    k_node<<<NQT/32, 256, 0, stream>>>(hc, agg,
        nW1p + (size_t)j*32768, nb1 + (size_t)j*128,
        nW2p + (size_t)j*16384, nb2 + (size_t)j*128,
        lng + (size_t)j*128,    lnb + (size_t)j*128, hn,
        produce, temb,
        W1bcp + (size_t)jn*65536, mb1 + (size_t)jn*256,
        W1ap + (size_t)jn*32768,
        PtgtF, PsrcQ);
    float* tmp = hc; hc = hn; hn = tmp;
  }
  k_out<<<NQT/16, 256, 0, stream>>>(hc, vel, voW1, vob1, voW2, vob2, out);
}

// Round 13
// 1342.130 us; speedup vs baseline: 1.6196x; 1.6196x over previous
//
#include <hip/hip_runtime.h>

#define NQT 16384
#define NAT 512
#define EAQ 131072
#define EQQ 262144

typedef short short8 __attribute__((ext_vector_type(8)));
typedef float float4v __attribute__((ext_vector_type(4)));

__device__ __forceinline__ float silu_f(float x){ return x / (1.f + __expf(-x)); }

__device__ __forceinline__ short f2bf(float f){
  union { float f; unsigned u; } v; v.f = f;
  unsigned r = v.u + 0x7fff + ((v.u >> 16) & 1);
  return (short)(r >> 16);
}
__device__ __forceinline__ float bf2f(short s){
  union { unsigned u; float f; } v;
  v.u = ((unsigned)(unsigned short)s) << 16;
  return v.f;
}

// ---------------- counting sort by tgt (both edge sets) ----------------
__global__ __launch_bounds__(256) void k_hist2(
    const int* __restrict__ ta, const int* __restrict__ tq,
    int* __restrict__ ha, int* __restrict__ hq)
{
  int i = blockIdx.x*256 + threadIdx.x;
  atomicAdd(&hq[tq[i]], 1);
  if (i < EAQ) atomicAdd(&ha[ta[i]], 1);
}

__global__ __launch_bounds__(256) void k_scan2(int* __restrict__ ha, int* __restrict__ hq)
{
  int* hist = (blockIdx.x == 0) ? ha : hq;
  __shared__ int part[256];
  int t = threadIdx.x;
  int base = t * 64;
  int s = 0;
  for (int i = 0; i < 64; i++) s += hist[base + i];
  part[t] = s;
  __syncthreads();
  for (int off = 1; off < 256; off <<= 1){
    int v = (t >= off) ? part[t - off] : 0;
    __syncthreads();
    part[t] += v;
    __syncthreads();
  }
  int run = (t == 0) ? 0 : part[t-1];
  for (int i = 0; i < 64; i++){
    int h = hist[base + i];
    hist[base + i] = run;
    run += h;
  }
}

__global__ __launch_bounds__(256) void k_place2(
    const int* __restrict__ sa, const int* __restrict__ ta,
    const int* __restrict__ sq, const int* __restrict__ tq,
    int* __restrict__ ca, int* __restrict__ cq,
    int2* __restrict__ da, int2* __restrict__ dq)
{
  int i = blockIdx.x*256 + threadIdx.x;
  { int tg = tq[i]; int pos = atomicAdd(&cq[tg], 1); dq[pos] = make_int2(sq[i], tg); }
  if (i < EAQ){ int tg = ta[i]; int pos = atomicAdd(&ca[tg], 1); da[pos] = make_int2(sa[i], tg); }
}

// ---------------- weight packer (all jobs, one launch) ----------------
// layout: [ntiles][ksteps][64 lanes][8]; lane gives B[k=kk*32+(lane>>4)*8+j][n=nt*16+(lane&15)]
__device__ __forceinline__ void pack_one(
    const float* __restrict__ W, short* __restrict__ out,
    int rows, int cols, int ksteps, int ntiles, int idx, int mode)
{
  int l8   = idx & 7;
  int lane = (idx >> 3) & 63;
  int kk   = (idx >> 9) % ksteps;
  int nt   = ((idx >> 9) / ksteps) % ntiles;
  int j    = idx / (512 * ksteps * ntiles);
  int k = kk*32 + (lane >> 4)*8 + l8;
  if (mode == 1) k += (k >= 256);
  else if (mode == 2) k = (k < 128) ? k + 128 : k + 129;   // [h_tgt | temb] rows of W1
  int n = nt*16 + (lane & 15);
  out[idx] = f2bf(W[(size_t)j*rows*cols + (size_t)k*cols + n]);
}

__global__ __launch_bounds__(256) void k_packall(
    const float* __restrict__ mW1, const float* __restrict__ mW2,
    const float* __restrict__ cW1, const float* __restrict__ nW1,
    const float* __restrict__ nW2, const float* __restrict__ tW1,
    const float* __restrict__ tW2,
    short* W1ap, short* W1bcp, short* W2p, short* W3p,
    short* nW1p, short* nW2p, short* tW1p, short* tW2p)
{
  int b = blockIdx.x, t = threadIdx.x;
  if (b < 1024){ pack_one(mW1, W1ap, 385,256,4,16, b*256+t, 0); return; } b -= 1024;
  if (b < 2048){ pack_one(mW1, W1bcp,385,256,8,16, b*256+t, 2); return; } b -= 2048;
  if (b < 1024){ pack_one(mW2, W2p,  256,128,8, 8, b*256+t, 0); return; } b -= 1024;
  if (b <  256){ pack_one(cW1, W3p,  128, 64,4, 4, b*256+t, 0); return; } b -=  256;
  if (b < 1024){ pack_one(nW1, nW1p, 256,128,8, 8, b*256+t, 0); return; } b -= 1024;
  if (b <  512){ pack_one(nW2, nW2p, 128,128,4, 8, b*256+t, 0); return; } b -=  512;
  if (b <  256){ pack_one(tW1, tW1p, 128,512,4,32, b*256+t, 0); return; } b -=  256;
  pack_one(tW2, tW2p, 512,128,16,8, b*256+t, 0);
}

// ---------------- initial operand production: Ptgt_0 (f32) + all 4 AQ Psrc (bf16) ----------------
__global__ __launch_bounds__(256) void k_pre0(
    const float* __restrict__ hA, const float* __restrict__ temb,
    const float* __restrict__ mb1_0, const short* __restrict__ W1bcp0,
    const float* __restrict__ h_atom, const short* __restrict__ W1ap_base,
    float* __restrict__ Ptgt, short* __restrict__ psrc_aq)
{
  int t = threadIdx.x;
  int lane = t & 63, w = t >> 6;
  int mrow = lane & 15, quad = lane >> 4;
  int b = blockIdx.x;

  if (b < NQT/64){
    int m0 = b*64 + w*16;
    short8 areg[8];
    #pragma unroll
    for (int kk = 0; kk < 8; kk++){
      int k = kk*32 + quad*8;
      const float* bp = (kk >= 4) ? (temb + (size_t)(m0+mrow)*128 + (k - 128))
                                  : (hA   + (size_t)(m0+mrow)*128 + k);
      float4 f0 = *(const float4*)(bp);
      float4 f1 = *(const float4*)(bp + 4);
      short8 s;
      s[0]=f2bf(f0.x); s[1]=f2bf(f0.y); s[2]=f2bf(f0.z); s[3]=f2bf(f0.w);
      s[4]=f2bf(f1.x); s[5]=f2bf(f1.y); s[6]=f2bf(f1.z); s[7]=f2bf(f1.w);
      areg[kk] = s;
    }
    #pragma unroll
    for (int nt = 0; nt < 16; nt++){
      float4v acc = {0.f,0.f,0.f,0.f};
      const short8* Bb = (const short8*)(W1bcp0 + ((size_t)nt*8)*512 + lane*8);
      #pragma unroll
      for (int kk = 0; kk < 8; kk++)
        acc = __builtin_amdgcn_mfma_f32_16x16x32_bf16(areg[kk], Bb[kk*64], acc, 0, 0, 0);
      float bv = mb1_0[nt*16 + mrow];
      #pragma unroll
      for (int r = 0; r < 4; r++)
        Ptgt[(size_t)(m0 + quad*4 + r)*256 + nt*16 + mrow] = acc[r] + bv;
    }
  } else {
    int bb = b - NQT/64;
    int idx = bb >> 3;                    // AQ layer slot 0..3 -> layer j=2*idx
    int m0 = (bb & 7)*64 + w*16;
    const short* Wp = W1ap_base + (size_t)(2*idx)*32768;
    short8 areg[4];
    #pragma unroll
    for (int kk = 0; kk < 4; kk++){
      const float* bp = h_atom + (size_t)(m0+mrow)*128 + kk*32 + quad*8;
      float4 f0 = *(const float4*)(bp);
      float4 f1 = *(const float4*)(bp + 4);
      short8 s;
      s[0]=f2bf(f0.x); s[1]=f2bf(f0.y); s[2]=f2bf(f0.z); s[3]=f2bf(f0.w);
      s[4]=f2bf(f1.x); s[5]=f2bf(f1.y); s[6]=f2bf(f1.z); s[7]=f2bf(f1.w);
      areg[kk] = s;
    }
    #pragma unroll
    for (int nt = 0; nt < 16; nt++){
      float4v acc = {0.f,0.f,0.f,0.f};
      const short8* Bb = (const short8*)(Wp + ((size_t)nt*4)*512 + lane*8);
      #pragma unroll
      for (int kk = 0; kk < 4; kk++)
        acc = __builtin_amdgcn_mfma_f32_16x16x32_bf16(areg[kk], Bb[kk*64], acc, 0, 0, 0);
      #pragma unroll
      for (int r = 0; r < 4; r++)
        psrc_aq[(size_t)idx*131072 + (size_t)(m0 + quad*4 + r)*256 + nt*16 + mrow] = f2bf(acc[r]);
    }
  }
}

// ---------------- h_atom ----------------
__global__ __launch_bounds__(128) void k_hatom(
    const float* __restrict__ feat, const float* __restrict__ W,
    const float* __restrict__ b, float* __restrict__ out)
{
  __shared__ float sf[256];
  int n = blockIdx.x, t = threadIdx.x;
  sf[t]       = feat[n*256 + t];
  sf[t + 128] = feat[n*256 + 128 + t];
  __syncthreads();
  float acc = b[t];
  for (int k = 0; k < 256; k++) acc += sf[k] * W[k*128 + t];
  out[n*128 + t] = acc;
}

// ---------------- t_emb (MFMA) ----------------
__global__ __launch_bounds__(256) void k_temb(
    const float* __restrict__ tq,
    const short* __restrict__ W1p, const float* __restrict__ b1,
    const short* __restrict__ W2p, const float* __restrict__ b2,
    float* __restrict__ temb)
{
  __shared__ __align__(16) short A[32*136];
  __shared__ __align__(16) short B[32*528];
  int t = threadIdx.x;
  int n0 = blockIdx.x * 32;

  {
    int row = t >> 3, l = t & 7;
    float tv = tq[n0 + row];
    short* o = A + row*136;
    #pragma unroll
    for (int i = 0; i < 16; i++){
      int k = l*16 + i;
      int h = k & 63;
      float freq = __expf(-9.210340371976184f * (float)h * (1.f/63.f));
      float a = tv * freq;
      float v = (k < 64) ? __sinf(a) : __cosf(a);
      o[k] = f2bf(v);
    }
  }
  __syncthreads();

  int lane = t & 63, w = t >> 6;
  int mrow = lane & 15, quad = lane >> 4;

  for (int nti = 0; nti < 8; nti++){
    int nt = w*8 + nti;
    #pragma unroll
    for (int mt = 0; mt < 2; mt++){
      float4v acc = {0.f,0.f,0.f,0.f};
      const short8* Ab = (const short8*)(A + (mt*16 + mrow)*136 + quad*8);
      const short8* Bb = (const short8*)(W1p + (size_t)nt*4*512 + lane*8);
      #pragma unroll
      for (int kk = 0; kk < 4; kk++)
        acc = __builtin_amdgcn_mfma_f32_16x16x32_bf16(Ab[kk*4], Bb[kk*64], acc, 0, 0, 0);
      int n = nt*16 + mrow;
      float b1n = b1[n];
      #pragma unroll
      for (int r = 0; r < 4; r++)
        B[(mt*16 + quad*4 + r)*528 + n] = f2bf(silu_f(acc[r] + b1n));
    }
  }
  __syncthreads();

  #pragma unroll
  for (int nti = 0; nti < 2; nti++){
    int nt = w*2 + nti;
    #pragma unroll
    for (int mt = 0; mt < 2; mt++){
      float4v acc = {0.f,0.f,0.f,0.f};
      const short8* Ab = (const short8*)(B + (mt*16 + mrow)*528 + quad*8);
      const short8* Bb = (const short8*)(W2p + (size_t)nt*16*512 + lane*8);
      #pragma unroll
      for (int kk = 0; kk < 16; kk++)
        acc = __builtin_amdgcn_mfma_f32_16x16x32_bf16(Ab[kk*4], Bb[kk*64], acc, 0, 0, 0);
      int n = nt*16 + mrow;
      float b2n = b2[n];
      #pragma unroll
      for (int r = 0; r < 4; r++)
        temb[(size_t)(n0 + mt*16 + quad*4 + r)*128 + n] = acc[r] + b2n;
    }
  }
}

// ---------------- h init (R10 form: 1 node / 128 threads) ----------------
__global__ __launch_bounds__(128) void k_hinit(
    const float* __restrict__ x_t, const float* __restrict__ atom_pos,
    const float* __restrict__ W1, const float* __restrict__ b1,
    const float* __restrict__ W2, const float* __restrict__ b2,
    float* __restrict__ h)
{
  __shared__ float sh[128];
  __shared__ float sld;
  int n = blockIdx.x, t = threadIdx.x;
  float qx = x_t[n*3], qy = x_t[n*3+1], qz = x_t[n*3+2];
  float part = 0.f;
  if (t < 64){
    int a = (n >> 11)*64 + t;
    float dx = qx - atom_pos[a*3];
    float dy = qy - atom_pos[a*3+1];
    float dz = qz - atom_pos[a*3+2];
    part = dx*dx + dy*dy + dz*dz;
  }
  #pragma unroll
  for (int off = 32; off; off >>= 1) part += __shfl_down(part, off);
  if (t == 0) sld = log1pf(sqrtf(part * (1.f/64.f)) * 0.125f);
  __syncthreads();
  float ld = sld;
  sh[t] = silu_f(ld * W1[t] + b1[t]);
  __syncthreads();
  float acc = b2[t];
  for (int k = 0; k < 128; k++) acc += sh[k] * W2[k*128 + t];
  h[(size_t)n*128 + t] = acc;
}

// ---------------- EGNN edge kernel: 256 threads / 32 edges (R10 shape, f32 Ptgt) ----------------
__global__ __launch_bounds__(256) void k_edge(
    const short* __restrict__ Psrc, const float* __restrict__ Ptgt,
    const float* __restrict__ pos_src, const float* __restrict__ pos_tgt,
    const int2* __restrict__ sdesc,
    const float* __restrict__ w1sq,
    const short* __restrict__ W2p, const float* __restrict__ b2,
    const short* __restrict__ W3p, const float* __restrict__ b3,
    const float* __restrict__ W4,  const float* __restrict__ b4,
    float* __restrict__ agg, float* __restrict__ vel)
{
  __shared__ __align__(16) short A2[32*264];   // pre1 bf16 str264; later msgf f32 str132; later h3 f32 str68
  __shared__ __align__(16) short A3[32*136];   // msg bf16 str 136
  __shared__ float rel_s[32*3];
  __shared__ int   tgt_s[32];
  float* msgf = (float*)A2;
  float* h3   = (float*)A2;

  int t = threadIdx.x;
  int e0 = blockIdx.x * 32;

  // ---- stage: pre1 = Psrc[src] + Ptgt[tgt](f32, b1 folded) + sq*w1sq -> silu -> A2 ----
  {
    int e = t >> 3, l = t & 7;
    int2 d = sdesc[e0 + e];
    int src = d.x, tgt = d.y;
    float rx = pos_tgt[tgt*3+0] - pos_src[src*3+0];
    float ry = pos_tgt[tgt*3+1] - pos_src[src*3+1];
    float rz = pos_tgt[tgt*3+2] - pos_src[src*3+2];
    float sqv = rx*rx + ry*ry + rz*rz;
    if (l == 0){
      rel_s[e*3+0]=rx; rel_s[e*3+1]=ry; rel_s[e*3+2]=rz;
      tgt_s[e] = tgt;
    }
    const short8*  ps = (const short8*)(Psrc + (size_t)src*256);
    const float4*  pt = (const float4*)(Ptgt + (size_t)tgt*256);
    #pragma unroll
    for (int c = 0; c < 4; c++){
      int ci = c*8 + l;
      int n0 = ci*8;
      short8 a = ps[ci];
      float4 b0 = pt[ci*2], b1v = pt[ci*2+1];
      float4 w0 = *(const float4*)(w1sq + n0);
      float4 w1 = *(const float4*)(w1sq + n0 + 4);
      short8 r;
      r[0] = f2bf(silu_f(bf2f(a[0]) + b0.x  + sqv*w0.x));
      r[1] = f2bf(silu_f(bf2f(a[1]) + b0.y  + sqv*w0.y));
      r[2] = f2bf(silu_f(bf2f(a[2]) + b0.z  + sqv*w0.z));
      r[3] = f2bf(silu_f(bf2f(a[3]) + b0.w  + sqv*w0.w));
      r[4] = f2bf(silu_f(bf2f(a[4]) + b1v.x + sqv*w1.x));
      r[5] = f2bf(silu_f(bf2f(a[5]) + b1v.y + sqv*w1.y));
      r[6] = f2bf(silu_f(bf2f(a[6]) + b1v.z + sqv*w1.z));
      r[7] = f2bf(silu_f(bf2f(a[7]) + b1v.w + sqv*w1.w));
      *(short8*)(A2 + e*264 + n0) = r;
    }
  }
  __syncthreads();

  int lane = t & 63, w = t >> 6;
  int mrow = lane & 15, quad = lane >> 4;

  // ---- GEMM2: hoist A-fragments to registers ONCE, reuse across both n-tiles ----
  short8 afr[2][8];
  #pragma unroll
  for (int mt = 0; mt < 2; mt++){
    const short8* Ab = (const short8*)(A2 + (mt*16 + mrow)*264 + quad*8);
    #pragma unroll
    for (int kk = 0; kk < 8; kk++)
      afr[mt][kk] = Ab[kk*4];
  }
  float4v acc2[2][2];
  #pragma unroll
  for (int nti = 0; nti < 2; nti++){
    int nt = w*2 + nti;
    #pragma unroll
    for (int mt = 0; mt < 2; mt++){
      float4v acc = {0.f,0.f,0.f,0.f};
      const short8* Bb = (const short8*)(W2p + (size_t)nt*8*512 + lane*8);
      #pragma unroll
      for (int kk = 0; kk < 8; kk++)
        acc = __builtin_amdgcn_mfma_f32_16x16x32_bf16(afr[mt][kk], Bb[kk*64], acc, 0, 0, 0);
      acc2[nti][mt] = acc;
    }
  }
  __syncthreads();   // A2 reads done — region becomes msgf

  // ---- epilogue: silu -> msgf (f32) + A3 (bf16) ----
  #pragma unroll
  for (int nti = 0; nti < 2; nti++){
    int n = (w*2 + nti)*16 + mrow;
    float b2n = b2[n];
    #pragma unroll
    for (int mt = 0; mt < 2; mt++){
      #pragma unroll
      for (int r = 0; r < 4; r++){
        int e = mt*16 + quad*4 + r;
        float v = silu_f(acc2[nti][mt][r] + b2n);
        msgf[e*132 + n] = v;
        A3[e*136 + n]   = f2bf(v);
      }
    }
  }
  __syncthreads();

  // ---- GEMM3 MFMAs first (regs only, overlaps reduce latency) ----
  float4v acc3[2];
  {
    int nt = w;
    #pragma unroll
    for (int mt = 0; mt < 2; mt++){
      float4v acc = {0.f,0.f,0.f,0.f};
      const short8* Ab = (const short8*)(A3 + (mt*16 + mrow)*136 + quad*8);
      const short8* Bb = (const short8*)(W3p + (size_t)nt*4*512 + lane*8);
      #pragma unroll
      for (int kk = 0; kk < 4; kk++)
        acc = __builtin_amdgcn_mfma_f32_16x16x32_bf16(Ab[kk*4], Bb[kk*64], acc, 0, 0, 0);
      acc3[mt] = acc;
    }
  }

  // ---- segmented agg reduction (sorted by tgt), f32, 2 groups of 16 ----
  {
    int c = t & 127, hh = t >> 7;
    int eb = hh*16;
    float run = 0.f;
    int cur = tgt_s[eb];
    for (int e = eb; e < eb + 16; e++){
      int tg = tgt_s[e];
      if (tg != cur){
        atomicAdd(&agg[(size_t)cur*128 + c], run);
        run = 0.f; cur = tg;
      }
      run += msgf[e*132 + c];
    }
    atomicAdd(&agg[(size_t)cur*128 + c], run);
  }
  __syncthreads();   // msgf reads done — region becomes h3

  // ---- write h3 ----
  {
    int n = w*16 + mrow;
    float b3n = b3[n];
    #pragma unroll
    for (int mt = 0; mt < 2; mt++){
      #pragma unroll
      for (int r = 0; r < 4; r++){
        int e = mt*16 + quad*4 + r;
        h3[e*68 + n] = silu_f(acc3[mt][r] + b3n);
      }
    }
  }
  __syncthreads();

  // ---- GEMM4 (f32 dot-64) + tanh + vel scatter ----
  {
    int e = t >> 3, l = t & 7;
    float p = 0.f;
    #pragma unroll
    for (int i = 0; i < 8; i++){
      int k = l + 8*i;
      p += h3[e*68 + k] * W4[k];
    }
    p += __shfl_xor(p, 1);
    p += __shfl_xor(p, 2);
    p += __shfl_xor(p, 4);
    if (l == 0){
      float wv = tanhf(p + b4[0]);
      int tg = tgt_s[e];
      atomicAdd(&vel[tg*3+0], wv*rel_s[e*3+0]);
      atomicAdd(&vel[tg*3+1], wv*rel_s[e*3+1]);
      atomicAdd(&vel[tg*3+2], wv*rel_s[e*3+2]);
    }
  }
}

// ---------------- node update (MFMA) + fused next-layer operand production ----------------
__global__ __launch_bounds__(256) void k_node(
    const float* __restrict__ h, float* __restrict__ agg,
    const short* __restrict__ W1p, const float* __restrict__ b1,
    const short* __restrict__ W2p, const float* __restrict__ b2,
    const float* __restrict__ g, const float* __restrict__ bb_,
    float* __restrict__ h_out,
    int produce,                                   // 0 none, 1 Ptgt, 2 Ptgt+Psrc
    const float* __restrict__ temb,
    const short* __restrict__ W1bcN, const float* __restrict__ mb1N,
    const short* __restrict__ W1aN,
    float* __restrict__ Ptgt, short* __restrict__ PsrcQ)
{
  __shared__ __align__(16) short A[32*264];   // u bf16 str264; later r f32 str132
  __shared__ __align__(16) short B[32*136];   // hid bf16 str136
  __shared__ __align__(16) short S[32*264];   // [h_new | temb] bf16 str264 (production)
  float* r = (float*)A;
  int t = threadIdx.x;
  int n0 = blockIdx.x * 32;

  { // stage u = [h|agg] bf16, zero agg; stage temb -> S cols 128..255
    int row = t >> 3, l = t & 7;
    const float4* hr = (const float4*)(h + (size_t)(n0+row)*128);
    float4*       ar = (float4*)(agg + (size_t)(n0+row)*128);
    const float4* te = (const float4*)(temb + (size_t)(n0+row)*128);
    short* o = A + row*264;
    short* so = S + row*264 + 128;
    float4 z = make_float4(0.f,0.f,0.f,0.f);
    #pragma unroll
    for (int i = 0; i < 4; i++){
      int k4 = l + 8*i;
      float4 a = hr[k4];
      o[k4*4+0]=f2bf(a.x); o[k4*4+1]=f2bf(a.y); o[k4*4+2]=f2bf(a.z); o[k4*4+3]=f2bf(a.w);
      float4 b = ar[k4];
      o[128 + k4*4+0]=f2bf(b.x); o[128 + k4*4+1]=f2bf(b.y);
      o[128 + k4*4+2]=f2bf(b.z); o[128 + k4*4+3]=f2bf(b.w);
      ar[k4] = z;
      if (produce){
        float4 c = te[k4];
        so[k4*4+0]=f2bf(c.x); so[k4*4+1]=f2bf(c.y);
        so[k4*4+2]=f2bf(c.z); so[k4*4+3]=f2bf(c.w);
      }
    }
  }
  __syncthreads();

  int lane = t & 63, w = t >> 6;
  int mrow = lane & 15, quad = lane >> 4;

  // GEMM_A: (32x256)@(256x128)
  float4v accA[2][2];
  #pragma unroll
  for (int nti = 0; nti < 2; nti++){
    int nt = w*2 + nti;
    #pragma unroll
    for (int mt = 0; mt < 2; mt++){
      float4v acc = {0.f,0.f,0.f,0.f};
      const short8* Ab = (const short8*)(A + (mt*16 + mrow)*264 + quad*8);
      const short8* Bb = (const short8*)(W1p + (size_t)nt*8*512 + lane*8);
      #pragma unroll
      for (int kk = 0; kk < 8; kk++)
        acc = __builtin_amdgcn_mfma_f32_16x16x32_bf16(Ab[kk*4], Bb[kk*64], acc, 0, 0, 0);
      accA[nti][mt] = acc;
    }
  }
  __syncthreads();

  #pragma unroll
  for (int nti = 0; nti < 2; nti++){
    int n = (w*2 + nti)*16 + mrow;
    float b1n = b1[n];
    #pragma unroll
    for (int mt = 0; mt < 2; mt++){
      #pragma unroll
      for (int rr = 0; rr < 4; rr++){
        int e = mt*16 + quad*4 + rr;
        B[e*136 + n] = f2bf(silu_f(accA[nti][mt][rr] + b1n));
      }
    }
  }
  __syncthreads();

  // GEMM_B: (32x128)@(128x128) -> residual -> r
  #pragma unroll
  for (int nti = 0; nti < 2; nti++){
    int nt = w*2 + nti;
    #pragma unroll
    for (int mt = 0; mt < 2; mt++){
      float4v acc = {0.f,0.f,0.f,0.f};
      const short8* Ab = (const short8*)(B + (mt*16 + mrow)*136 + quad*8);
      const short8* Bb = (const short8*)(W2p + (size_t)nt*4*512 + lane*8);
      #pragma unroll
      for (int kk = 0; kk < 4; kk++)
        acc = __builtin_amdgcn_mfma_f32_16x16x32_bf16(Ab[kk*4], Bb[kk*64], acc, 0, 0, 0);
      int n = nt*16 + mrow;
      float b2n = b2[n];
      #pragma unroll
      for (int rr = 0; rr < 4; rr++){
        int e = mt*16 + quad*4 + rr;
        r[e*132 + n] = h[(size_t)(n0+e)*128 + n] + acc[rr] + b2n;
      }
    }
  }
  __syncthreads();

  // LayerNorm -> h_out global + S cols 0..127 (bf16)
  {
    int lane2 = t & 63, wid = t >> 6;
    #pragma unroll
    for (int nn = 0; nn < 8; nn++){
      int row = wid*8 + nn;
      float a = r[row*132 + lane2], bv = r[row*132 + lane2 + 64];
      float s = a + bv, ss = a*a + bv*bv;
      #pragma unroll
      for (int off = 1; off < 64; off <<= 1){
        s  += __shfl_xor(s, off);
        ss += __shfl_xor(ss, off);
      }
      float mean = s * (1.f/128.f);
      float var  = ss * (1.f/128.f) - mean*mean;
      float rstd = rsqrtf(var + 1e-5f);
      float v0 = (a  - mean)*rstd*g[lane2]      + bb_[lane2];
      float v1 = (bv - mean)*rstd*g[lane2 + 64] + bb_[lane2 + 64];
      float* ho = h_out + (size_t)(n0+row)*128;
      ho[lane2]      = v0;
      ho[lane2 + 64] = v1;
      S[row*264 + lane2]      = f2bf(v0);
      S[row*264 + lane2 + 64] = f2bf(v1);
    }
  }
  if (!produce) return;
  __syncthreads();

  // ---- produce Ptgt_{j+1} (f32) = [h_new|temb] @ W1bcN + mb1N ----
  #pragma unroll
  for (int nti = 0; nti < 4; nti++){
    int nt = w*4 + nti;
    #pragma unroll
    for (int mt = 0; mt < 2; mt++){
      float4v acc = {0.f,0.f,0.f,0.f};
      const short8* Ab = (const short8*)(S + (mt*16 + mrow)*264 + quad*8);
      const short8* Bb = (const short8*)(W1bcN + (size_t)nt*8*512 + lane*8);
      #pragma unroll
      for (int kk = 0; kk < 8; kk++)
        acc = __builtin_amdgcn_mfma_f32_16x16x32_bf16(Ab[kk*4], Bb[kk*64], acc, 0, 0, 0);
      int n = nt*16 + mrow;
      float bv = mb1N[n];
      #pragma unroll
      for (int rr = 0; rr < 4; rr++)
        Ptgt[(size_t)(n0 + mt*16 + quad*4 + rr)*256 + n] = acc[rr] + bv;
    }
  }

  // ---- produce Psrc_{j+1} = h_new @ W1aN (QQ next layer only) ----
  if (produce == 2){
    #pragma unroll
    for (int nti = 0; nti < 4; nti++){
      int nt = w*4 + nti;
      #pragma unroll
      for (int mt = 0; mt < 2; mt++){
        float4v acc = {0.f,0.f,0.f,0.f};
        const short8* Ab = (const short8*)(S + (mt*16 + mrow)*264 + quad*8);
        const short8* Bb = (const short8*)(W1aN + (size_t)nt*4*512 + lane*8);
        #pragma unroll
        for (int kk = 0; kk < 4; kk++)
          acc = __builtin_amdgcn_mfma_f32_16x16x32_bf16(Ab[kk*4], Bb[kk*64], acc, 0, 0, 0);
        int n = nt*16 + mrow;
        #pragma unroll
        for (int rr = 0; rr < 4; rr++)
          PsrcQ[(size_t)(n0 + mt*16 + quad*4 + rr)*256 + n] = f2bf(acc[rr]);
      }
    }
  }
}

// ---------------- output (R10 form: 1 node / 128 threads) ----------------
__global__ __launch_bounds__(128) void k_out(
    const float* __restrict__ h, const float* __restrict__ vel,
    const float* __restrict__ W1, const float* __restrict__ b1,
    const float* __restrict__ W2, const float* __restrict__ b2,
    float* __restrict__ out)
{
  __shared__ float sh[128];
  __shared__ float spart[2];
  int n = blockIdx.x, t = threadIdx.x;
  sh[t] = h[(size_t)n*128 + t];
  __syncthreads();
  float acc = b1[t];
  for (int k = 0; k < 128; k++) acc += sh[k] * W1[k*128 + t];
  float p = silu_f(acc) * W2[t];
  #pragma unroll
  for (int off = 32; off; off >>= 1) p += __shfl_down(p, off);
  if ((t & 63) == 0) spart[t >> 6] = p;
  __syncthreads();
  if (t < 3){
    float scale = spart[0] + spart[1] + b2[0];
    out[n*3 + t] = vel[n*3 + t] * scale;
  }
}

extern "C" void kernel_launch(void* const* d_in, const int* in_sizes, int n_in,
                              void* d_out, int out_size, void* d_ws, size_t ws_size,
                              hipStream_t stream)
{
  const float* x_t       = (const float*)d_in[0];
  const float* t_query   = (const float*)d_in[1];
  const float* atom_pos  = (const float*)d_in[2];
  const float* atom_feat = (const float*)d_in[3];
  const int*   e_aq_s = (const int*)d_in[4];
  const int*   e_aq_t = (const int*)d_in[5];
  const int*   e_qq_s = (const int*)d_in[6];
  const int*   e_qq_t = (const int*)d_in[7];
  const float* apW  = (const float*)d_in[8];
  const float* apb  = (const float*)d_in[9];
  const float* tW1  = (const float*)d_in[10];
  const float* tb1  = (const float*)d_in[11];
  const float* tW2  = (const float*)d_in[12];
  const float* tb2  = (const float*)d_in[13];
  const float* qiW1 = (const float*)d_in[14];
  const float* qib1 = (const float*)d_in[15];
  const float* qiW2 = (const float*)d_in[16];
  const float* qib2 = (const float*)d_in[17];
  const float* mW1  = (const float*)d_in[18];
  const float* mb1  = (const float*)d_in[19];
  const float* mW2  = (const float*)d_in[20];
  const float* mb2  = (const float*)d_in[21];
  const float* cW1  = (const float*)d_in[22];
  const float* cb1  = (const float*)d_in[23];
  const float* cW2  = (const float*)d_in[24];
  const float* cb2  = (const float*)d_in[25];
  const float* nW1  = (const float*)d_in[26];
  const float* nb1  = (const float*)d_in[27];
  const float* nW2  = (const float*)d_in[28];
  const float* nb2  = (const float*)d_in[29];
  const float* lng  = (const float*)d_in[30];
  const float* lnb  = (const float*)d_in[31];
  const float* voW1 = (const float*)d_in[32];
  const float* vob1 = (const float*)d_in[33];
  const float* voW2 = (const float*)d_in[34];
  const float* vob2 = (const float*)d_in[35];
  float* out = (float*)d_out;

  float* ws     = (float*)d_ws;
  float* h_atom = ws;                        // 65536
  float* temb   = h_atom + 65536;            // 2097152
  float* hA     = temb + 2097152;
  float* hB     = hA + 2097152;
  float* agg    = hB + 2097152;              // contiguous with vel
  float* vel    = agg + 2097152;             // 49152
  short* W1ap   = (short*)(vel + 49152);     // 262144
  short* W1bcp  = W1ap + 262144;             // 524288
  short* W2p    = W1bcp + 524288;            // 262144
  short* W3p    = W2p + 262144;              // 65536
  short* nW1p   = W3p + 65536;               // 262144
  short* nW2p   = nW1p + 262144;             // 131072
  short* tW1p   = nW2p + 131072;             // 65536
  short* tW2p   = tW1p + 65536;              // 65536
  short* PsrcQ  = tW2p + 65536;              // 4194304 shorts
  short* psrc_aq= PsrcQ + 4194304;           // 524288 shorts
  float* PtgtF  = (float*)(psrc_aq + 524288);// 4194304 floats (f32 Ptgt)
  int*   hist_a = (int*)(PtgtF + 4194304);   // 16384 (contiguous with hist_q)
  int*   hist_q = hist_a + 16384;            // 16384
  int2*  desc_a = (int2*)(hist_q + 16384);   // EAQ
  int2*  desc_q = desc_a + EAQ;              // EQQ

  // ---- sort both edge sets ----
  hipMemsetAsync(hist_a, 0, 2*16384*sizeof(int), stream);
  k_hist2<<<EQQ/256, 256, 0, stream>>>(e_aq_t, e_qq_t, hist_a, hist_q);
  k_scan2<<<2, 256, 0, stream>>>(hist_a, hist_q);
  k_place2<<<EQQ/256, 256, 0, stream>>>(e_aq_s, e_aq_t, e_qq_s, e_qq_t,
                                        hist_a, hist_q, desc_a, desc_q);

  // ---- all weight packing in one launch ----
  k_packall<<<6400, 256, 0, stream>>>(mW1, mW2, cW1, nW1, nW2, tW1, tW2,
      W1ap, W1bcp, W2p, W3p, nW1p, nW2p, tW1p, tW2p);

  // zero agg + vel (contiguous)
  hipMemsetAsync(agg, 0, (size_t)(NQT*128 + NQT*3)*sizeof(float), stream);
  k_hatom<<<NAT, 128, 0, stream>>>(atom_feat, apW, apb, h_atom);
  k_temb<<<NQT/32, 256, 0, stream>>>(t_query, tW1p, tb1, tW2p, tb2, temb);
  k_hinit<<<NQT, 128, 0, stream>>>(x_t, atom_pos, qiW1, qib1, qiW2, qib2, hA);

  // initial operands: Ptgt (f32) for layer 0 + Psrc for all 4 AQ layers
  k_pre0<<<NQT/64 + 32, 256, 0, stream>>>(hA, temb, mb1, W1bcp, h_atom, W1ap,
                                          PtgtF, psrc_aq);

  float* hc = hA; float* hn = hB;
  for (int j = 0; j < 8; j++){
    int half = j & 1;                       // 0 = AQ, 1 = QQ
    const int2* dsc = half ? desc_q : desc_a;
    int E = half ? EQQ : EAQ;
    const short* psrc = half ? PsrcQ : (psrc_aq + (size_t)(j >> 1)*131072);

    k_edge<<<E/32, 256, 0, stream>>>(psrc, PtgtF,
        half ? x_t : atom_pos, x_t, dsc,
        mW1 + (size_t)j*385*256 + 65536,
        W2p + (size_t)j*32768, mb2 + (size_t)j*128,
        W3p + (size_t)j*8192,  cb1 + (size_t)j*64,
        cW2 + (size_t)j*64,    cb2 + (size_t)j,
        agg, vel);

    int jn = (j < 7) ? (j + 1) : 7;         // next-layer weights (dummy when produce=0)
    int produce = (j == 7) ? 0 : ((half == 0) ? 2 : 1);
    k_node<<<NQT/32, 256, 0, stream>>>(hc, agg,
        nW1p + (size_t)j*32768, nb1 + (size_t)j*128,
        nW2p + (size_t)j*16384, nb2 + (size_t)j*128,
        lng + (size_t)j*128,    lnb + (size_t)j*128, hn,
        produce, temb,
        W1bcp + (size_t)jn*65536, mb1 + (size_t)jn*256,
        W1ap + (size_t)jn*32768,
        PtgtF, PsrcQ);
    float* tmp = hc; hc = hn; hn = tmp;
  }
  k_out<<<NQT, 128, 0, stream>>>(hc, vel, voW1, vob1, voW2, vob2, out);
}

// Round 14
// 1290.855 us; speedup vs baseline: 1.6839x; 1.0397x over previous
//
#include <hip/hip_runtime.h>

#define NQT 16384
#define NAT 512
#define EAQ 131072
#define EQQ 262144

typedef short short8 __attribute__((ext_vector_type(8)));
typedef float float4v __attribute__((ext_vector_type(4)));

__device__ __forceinline__ float silu_f(float x){ return x / (1.f + __expf(-x)); }

__device__ __forceinline__ short f2bf(float f){
  union { float f; unsigned u; } v; v.f = f;
  unsigned r = v.u + 0x7fff + ((v.u >> 16) & 1);
  return (short)(r >> 16);
}
__device__ __forceinline__ float bf2f(short s){
  union { unsigned u; float f; } v;
  v.u = ((unsigned)(unsigned short)s) << 16;
  return v.f;
}

// ---------------- counting sort by tgt (both edge sets) ----------------
__global__ __launch_bounds__(256) void k_hist2(
    const int* __restrict__ ta, const int* __restrict__ tq,
    int* __restrict__ ha, int* __restrict__ hq)
{
  int i = blockIdx.x*256 + threadIdx.x;
  atomicAdd(&hq[tq[i]], 1);
  if (i < EAQ) atomicAdd(&ha[ta[i]], 1);
}

__global__ __launch_bounds__(256) void k_scan2(int* __restrict__ ha, int* __restrict__ hq)
{
  int* hist = (blockIdx.x == 0) ? ha : hq;
  __shared__ int part[256];
  int t = threadIdx.x;
  int base = t * 64;
  int s = 0;
  for (int i = 0; i < 64; i++) s += hist[base + i];
  part[t] = s;
  __syncthreads();
  for (int off = 1; off < 256; off <<= 1){
    int v = (t >= off) ? part[t - off] : 0;
    __syncthreads();
    part[t] += v;
    __syncthreads();
  }
  int run = (t == 0) ? 0 : part[t-1];
  for (int i = 0; i < 64; i++){
    int h = hist[base + i];
    hist[base + i] = run;
    run += h;
  }
}

__global__ __launch_bounds__(256) void k_place2(
    const int* __restrict__ sa, const int* __restrict__ ta,
    const int* __restrict__ sq, const int* __restrict__ tq,
    int* __restrict__ ca, int* __restrict__ cq,
    int2* __restrict__ da, int2* __restrict__ dq)
{
  int i = blockIdx.x*256 + threadIdx.x;
  { int tg = tq[i]; int pos = atomicAdd(&cq[tg], 1); dq[pos] = make_int2(sq[i], tg); }
  if (i < EAQ){ int tg = ta[i]; int pos = atomicAdd(&ca[tg], 1); da[pos] = make_int2(sa[i], tg); }
}

// ---------------- weight packer (all jobs, one launch) ----------------
// layout: [ntiles][ksteps][64 lanes][8]; lane gives B[k=kk*32+(lane>>4)*8+j][n=nt*16+(lane&15)]
__device__ __forceinline__ void pack_one(
    const float* __restrict__ W, short* __restrict__ out,
    int rows, int cols, int ksteps, int ntiles, int idx, int mode)
{
  int l8   = idx & 7;
  int lane = (idx >> 3) & 63;
  int kk   = (idx >> 9) % ksteps;
  int nt   = ((idx >> 9) / ksteps) % ntiles;
  int j    = idx / (512 * ksteps * ntiles);
  int k = kk*32 + (lane >> 4)*8 + l8;
  if (mode == 1) k += (k >= 256);
  else if (mode == 2) k = (k < 128) ? k + 128 : k + 129;   // [h_tgt | temb] rows of W1
  int n = nt*16 + (lane & 15);
  out[idx] = f2bf(W[(size_t)j*rows*cols + (size_t)k*cols + n]);
}

__global__ __launch_bounds__(256) void k_packall(
    const float* __restrict__ mW1, const float* __restrict__ mW2,
    const float* __restrict__ cW1, const float* __restrict__ nW1,
    const float* __restrict__ nW2, const float* __restrict__ tW1,
    const float* __restrict__ tW2,
    short* W1ap, short* W1bcp, short* W2p, short* W3p,
    short* nW1p, short* nW2p, short* tW1p, short* tW2p)
{
  int b = blockIdx.x, t = threadIdx.x;
  if (b < 1024){ pack_one(mW1, W1ap, 385,256,4,16, b*256+t, 0); return; } b -= 1024;
  if (b < 2048){ pack_one(mW1, W1bcp,385,256,8,16, b*256+t, 2); return; } b -= 2048;
  if (b < 1024){ pack_one(mW2, W2p,  256,128,8, 8, b*256+t, 0); return; } b -= 1024;
  if (b <  256){ pack_one(cW1, W3p,  128, 64,4, 4, b*256+t, 0); return; } b -=  256;
  if (b < 1024){ pack_one(nW1, nW1p, 256,128,8, 8, b*256+t, 0); return; } b -= 1024;
  if (b <  512){ pack_one(nW2, nW2p, 128,128,4, 8, b*256+t, 0); return; } b -=  512;
  if (b <  256){ pack_one(tW1, tW1p, 128,512,4,32, b*256+t, 0); return; } b -=  256;
  pack_one(tW2, tW2p, 512,128,16,8, b*256+t, 0);
}

// ---------------- initial operand production: Ptgt_0 + all 4 AQ Psrc ----------------
__global__ __launch_bounds__(256) void k_pre0(
    const float* __restrict__ hA, const float* __restrict__ temb,
    const float* __restrict__ mb1_0, const short* __restrict__ W1bcp0,
    const float* __restrict__ h_atom, const short* __restrict__ W1ap_base,
    short* __restrict__ Ptgt, short* __restrict__ psrc_aq)
{
  int t = threadIdx.x;
  int lane = t & 63, w = t >> 6;
  int mrow = lane & 15, quad = lane >> 4;
  int b = blockIdx.x;

  if (b < NQT/64){
    int m0 = b*64 + w*16;
    short8 areg[8];
    #pragma unroll
    for (int kk = 0; kk < 8; kk++){
      int k = kk*32 + quad*8;
      const float* bp = (kk >= 4) ? (temb + (size_t)(m0+mrow)*128 + (k - 128))
                                  : (hA   + (size_t)(m0+mrow)*128 + k);
      float4 f0 = *(const float4*)(bp);
      float4 f1 = *(const float4*)(bp + 4);
      short8 s;
      s[0]=f2bf(f0.x); s[1]=f2bf(f0.y); s[2]=f2bf(f0.z); s[3]=f2bf(f0.w);
      s[4]=f2bf(f1.x); s[5]=f2bf(f1.y); s[6]=f2bf(f1.z); s[7]=f2bf(f1.w);
      areg[kk] = s;
    }
    #pragma unroll
    for (int nt = 0; nt < 16; nt++){
      float4v acc = {0.f,0.f,0.f,0.f};
      const short8* Bb = (const short8*)(W1bcp0 + ((size_t)nt*8)*512 + lane*8);
      #pragma unroll
      for (int kk = 0; kk < 8; kk++)
        acc = __builtin_amdgcn_mfma_f32_16x16x32_bf16(areg[kk], Bb[kk*64], acc, 0, 0, 0);
      float bv = mb1_0[nt*16 + mrow];
      #pragma unroll
      for (int r = 0; r < 4; r++)
        Ptgt[(size_t)(m0 + quad*4 + r)*256 + nt*16 + mrow] = f2bf(acc[r] + bv);
    }
  } else {
    int bb = b - NQT/64;
    int idx = bb >> 3;                    // AQ layer slot 0..3 -> layer j=2*idx
    int m0 = (bb & 7)*64 + w*16;
    const short* Wp = W1ap_base + (size_t)(2*idx)*32768;
    short8 areg[4];
    #pragma unroll
    for (int kk = 0; kk < 4; kk++){
      const float* bp = h_atom + (size_t)(m0+mrow)*128 + kk*32 + quad*8;
      float4 f0 = *(const float4*)(bp);
      float4 f1 = *(const float4*)(bp + 4);
      short8 s;
      s[0]=f2bf(f0.x); s[1]=f2bf(f0.y); s[2]=f2bf(f0.z); s[3]=f2bf(f0.w);
      s[4]=f2bf(f1.x); s[5]=f2bf(f1.y); s[6]=f2bf(f1.z); s[7]=f2bf(f1.w);
      areg[kk] = s;
    }
    #pragma unroll
    for (int nt = 0; nt < 16; nt++){
      float4v acc = {0.f,0.f,0.f,0.f};
      const short8* Bb = (const short8*)(Wp + ((size_t)nt*4)*512 + lane*8);
      #pragma unroll
      for (int kk = 0; kk < 4; kk++)
        acc = __builtin_amdgcn_mfma_f32_16x16x32_bf16(areg[kk], Bb[kk*64], acc, 0, 0, 0);
      #pragma unroll
      for (int r = 0; r < 4; r++)
        psrc_aq[(size_t)idx*131072 + (size_t)(m0 + quad*4 + r)*256 + nt*16 + mrow] = f2bf(acc[r]);
    }
  }
}

// ---------------- h_atom ----------------
__global__ __launch_bounds__(128) void k_hatom(
    const float* __restrict__ feat, const float* __restrict__ W,
    const float* __restrict__ b, float* __restrict__ out)
{
  __shared__ float sf[256];
  int n = blockIdx.x, t = threadIdx.x;
  sf[t]       = feat[n*256 + t];
  sf[t + 128] = feat[n*256 + 128 + t];
  __syncthreads();
  float acc = b[t];
  for (int k = 0; k < 256; k++) acc += sf[k] * W[k*128 + t];
  out[n*128 + t] = acc;
}

// ---------------- t_emb (MFMA) ----------------
__global__ __launch_bounds__(256) void k_temb(
    const float* __restrict__ tq,
    const short* __restrict__ W1p, const float* __restrict__ b1,
    const short* __restrict__ W2p, const float* __restrict__ b2,
    float* __restrict__ temb)
{
  __shared__ __align__(16) short A[32*136];
  __shared__ __align__(16) short B[32*528];
  int t = threadIdx.x;
  int n0 = blockIdx.x * 32;

  {
    int row = t >> 3, l = t & 7;
    float tv = tq[n0 + row];
    short* o = A + row*136;
    #pragma unroll
    for (int i = 0; i < 16; i++){
      int k = l*16 + i;
      int h = k & 63;
      float freq = __expf(-9.210340371976184f * (float)h * (1.f/63.f));
      float a = tv * freq;
      float v = (k < 64) ? __sinf(a) : __cosf(a);
      o[k] = f2bf(v);
    }
  }
  __syncthreads();

  int lane = t & 63, w = t >> 6;
  int mrow = lane & 15, quad = lane >> 4;

  for (int nti = 0; nti < 8; nti++){
    int nt = w*8 + nti;
    #pragma unroll
    for (int mt = 0; mt < 2; mt++){
      float4v acc = {0.f,0.f,0.f,0.f};
      const short8* Ab = (const short8*)(A + (mt*16 + mrow)*136 + quad*8);
      const short8* Bb = (const short8*)(W1p + (size_t)nt*4*512 + lane*8);
      #pragma unroll
      for (int kk = 0; kk < 4; kk++)
        acc = __builtin_amdgcn_mfma_f32_16x16x32_bf16(Ab[kk*4], Bb[kk*64], acc, 0, 0, 0);
      int n = nt*16 + mrow;
      float b1n = b1[n];
      #pragma unroll
      for (int r = 0; r < 4; r++)
        B[(mt*16 + quad*4 + r)*528 + n] = f2bf(silu_f(acc[r] + b1n));
    }
  }
  __syncthreads();

  #pragma unroll
  for (int nti = 0; nti < 2; nti++){
    int nt = w*2 + nti;
    #pragma unroll
    for (int mt = 0; mt < 2; mt++){
      float4v acc = {0.f,0.f,0.f,0.f};
      const short8* Ab = (const short8*)(B + (mt*16 + mrow)*528 + quad*8);
      const short8* Bb = (const short8*)(W2p + (size_t)nt*16*512 + lane*8);
      #pragma unroll
      for (int kk = 0; kk < 16; kk++)
        acc = __builtin_amdgcn_mfma_f32_16x16x32_bf16(Ab[kk*4], Bb[kk*64], acc, 0, 0, 0);
      int n = nt*16 + mrow;
      float b2n = b2[n];
      #pragma unroll
      for (int r = 0; r < 4; r++)
        temb[(size_t)(n0 + mt*16 + quad*4 + r)*128 + n] = acc[r] + b2n;
    }
  }
}

// ---------------- h init ----------------
__global__ __launch_bounds__(128) void k_hinit(
    const float* __restrict__ x_t, const float* __restrict__ atom_pos,
    const float* __restrict__ W1, const float* __restrict__ b1,
    const float* __restrict__ W2, const float* __restrict__ b2,
    float* __restrict__ h)
{
  __shared__ float sh[128];
  __shared__ float sld;
  int n = blockIdx.x, t = threadIdx.x;
  float qx = x_t[n*3], qy = x_t[n*3+1], qz = x_t[n*3+2];
  float part = 0.f;
  if (t < 64){
    int a = (n >> 11)*64 + t;
    float dx = qx - atom_pos[a*3];
    float dy = qy - atom_pos[a*3+1];
    float dz = qz - atom_pos[a*3+2];
    part = dx*dx + dy*dy + dz*dz;
  }
  #pragma unroll
  for (int off = 32; off; off >>= 1) part += __shfl_down(part, off);
  if (t == 0) sld = log1pf(sqrtf(part * (1.f/64.f)) * 0.125f);
  __syncthreads();
  float ld = sld;
  sh[t] = silu_f(ld * W1[t] + b1[t]);
  __syncthreads();
  float acc = b2[t];
  for (int k = 0; k < 128; k++) acc += sh[k] * W2[k*128 + t];
  h[(size_t)n*128 + t] = acc;
}

// ---------------- EGNN edge kernel: 256 threads / 32 edges (R10 shape + A-frag hoist) ----------------
__global__ __launch_bounds__(256) void k_edge(
    const short* __restrict__ Psrc, const short* __restrict__ Ptgt,
    const float* __restrict__ pos_src, const float* __restrict__ pos_tgt,
    const int2* __restrict__ sdesc,
    const float* __restrict__ w1sq,
    const short* __restrict__ W2p, const float* __restrict__ b2,
    const short* __restrict__ W3p, const float* __restrict__ b3,
    const float* __restrict__ W4,  const float* __restrict__ b4,
    float* __restrict__ agg, float* __restrict__ vel)
{
  __shared__ __align__(16) short A2[32*264];   // pre1 bf16 str264; later msgf f32 str132; later h3 f32 str68
  __shared__ __align__(16) short A3[32*136];   // msg bf16 str 136
  __shared__ float rel_s[32*3];
  __shared__ int   tgt_s[32];
  float* msgf = (float*)A2;
  float* h3   = (float*)A2;

  int t = threadIdx.x;
  int e0 = blockIdx.x * 32;

  // ---- stage: pre1 = Psrc[src] + Ptgt[tgt](+b1 folded) + sq*w1sq -> silu -> A2 ----
  {
    int e = t >> 3, l = t & 7;
    int2 d = sdesc[e0 + e];
    int src = d.x, tgt = d.y;
    float rx = pos_tgt[tgt*3+0] - pos_src[src*3+0];
    float ry = pos_tgt[tgt*3+1] - pos_src[src*3+1];
    float rz = pos_tgt[tgt*3+2] - pos_src[src*3+2];
    float sqv = rx*rx + ry*ry + rz*rz;
    if (l == 0){
      rel_s[e*3+0]=rx; rel_s[e*3+1]=ry; rel_s[e*3+2]=rz;
      tgt_s[e] = tgt;
    }
    const short8* ps = (const short8*)(Psrc + (size_t)src*256);
    const short8* pt = (const short8*)(Ptgt + (size_t)tgt*256);
    #pragma unroll
    for (int c = 0; c < 4; c++){
      int ci = c*8 + l;
      int n0 = ci*8;
      short8 a = ps[ci], b = pt[ci];
      float4 w0 = *(const float4*)(w1sq + n0);
      float4 w1 = *(const float4*)(w1sq + n0 + 4);
      short8 r;
      r[0] = f2bf(silu_f(bf2f(a[0]) + bf2f(b[0]) + sqv*w0.x));
      r[1] = f2bf(silu_f(bf2f(a[1]) + bf2f(b[1]) + sqv*w0.y));
      r[2] = f2bf(silu_f(bf2f(a[2]) + bf2f(b[2]) + sqv*w0.z));
      r[3] = f2bf(silu_f(bf2f(a[3]) + bf2f(b[3]) + sqv*w0.w));
      r[4] = f2bf(silu_f(bf2f(a[4]) + bf2f(b[4]) + sqv*w1.x));
      r[5] = f2bf(silu_f(bf2f(a[5]) + bf2f(b[5]) + sqv*w1.y));
      r[6] = f2bf(silu_f(bf2f(a[6]) + bf2f(b[6]) + sqv*w1.z));
      r[7] = f2bf(silu_f(bf2f(a[7]) + bf2f(b[7]) + sqv*w1.w));
      *(short8*)(A2 + e*264 + n0) = r;
    }
  }
  __syncthreads();

  int lane = t & 63, w = t >> 6;
  int mrow = lane & 15, quad = lane >> 4;

  // ---- GEMM2: hoist A-fragments to registers ONCE, reuse across both n-tiles ----
  short8 afr[2][8];
  #pragma unroll
  for (int mt = 0; mt < 2; mt++){
    const short8* Ab = (const short8*)(A2 + (mt*16 + mrow)*264 + quad*8);
    #pragma unroll
    for (int kk = 0; kk < 8; kk++)
      afr[mt][kk] = Ab[kk*4];
  }
  float4v acc2[2][2];
  #pragma unroll
  for (int nti = 0; nti < 2; nti++){
    int nt = w*2 + nti;
    #pragma unroll
    for (int mt = 0; mt < 2; mt++){
      float4v acc = {0.f,0.f,0.f,0.f};
      const short8* Bb = (const short8*)(W2p + (size_t)nt*8*512 + lane*8);
      #pragma unroll
      for (int kk = 0; kk < 8; kk++)
        acc = __builtin_amdgcn_mfma_f32_16x16x32_bf16(afr[mt][kk], Bb[kk*64], acc, 0, 0, 0);
      acc2[nti][mt] = acc;
    }
  }
  __syncthreads();   // A2 reads done — region becomes msgf

  // ---- epilogue: silu -> msgf (f32) + A3 (bf16) ----
  #pragma unroll
  for (int nti = 0; nti < 2; nti++){
    int n = (w*2 + nti)*16 + mrow;
    float b2n = b2[n];
    #pragma unroll
    for (int mt = 0; mt < 2; mt++){
      #pragma unroll
      for (int r = 0; r < 4; r++){
        int e = mt*16 + quad*4 + r;
        float v = silu_f(acc2[nti][mt][r] + b2n);
        msgf[e*132 + n] = v;
        A3[e*136 + n]   = f2bf(v);
      }
    }
  }
  __syncthreads();

  // ---- GEMM3 MFMAs first (regs only, overlaps reduce latency) ----
  float4v acc3[2];
  {
    int nt = w;
    #pragma unroll
    for (int mt = 0; mt < 2; mt++){
      float4v acc = {0.f,0.f,0.f,0.f};
      const short8* Ab = (const short8*)(A3 + (mt*16 + mrow)*136 + quad*8);
      const short8* Bb = (const short8*)(W3p + (size_t)nt*4*512 + lane*8);
      #pragma unroll
      for (int kk = 0; kk < 4; kk++)
        acc = __builtin_amdgcn_mfma_f32_16x16x32_bf16(Ab[kk*4], Bb[kk*64], acc, 0, 0, 0);
      acc3[mt] = acc;
    }
  }

  // ---- segmented agg reduction (sorted by tgt), f32, 2 groups of 16 ----
  {
    int c = t & 127, hh = t >> 7;
    int eb = hh*16;
    float run = 0.f;
    int cur = tgt_s[eb];
    for (int e = eb; e < eb + 16; e++){
      int tg = tgt_s[e];
      if (tg != cur){
        atomicAdd(&agg[(size_t)cur*128 + c], run);
        run = 0.f; cur = tg;
      }
      run += msgf[e*132 + c];
    }
    atomicAdd(&agg[(size_t)cur*128 + c], run);
  }
  __syncthreads();   // msgf reads done — region becomes h3

  // ---- write h3 ----
  {
    int n = w*16 + mrow;
    float b3n = b3[n];
    #pragma unroll
    for (int mt = 0; mt < 2; mt++){
      #pragma unroll
      for (int r = 0; r < 4; r++){
        int e = mt*16 + quad*4 + r;
        h3[e*68 + n] = silu_f(acc3[mt][r] + b3n);
      }
    }
  }
  __syncthreads();

  // ---- GEMM4 (f32 dot-64) + tanh + vel scatter ----
  {
    int e = t >> 3, l = t & 7;
    float p = 0.f;
    #pragma unroll
    for (int i = 0; i < 8; i++){
      int k = l + 8*i;
      p += h3[e*68 + k] * W4[k];
    }
    p += __shfl_xor(p, 1);
    p += __shfl_xor(p, 2);
    p += __shfl_xor(p, 4);
    if (l == 0){
      float wv = tanhf(p + b4[0]);
      int tg = tgt_s[e];
      atomicAdd(&vel[tg*3+0], wv*rel_s[e*3+0]);
      atomicAdd(&vel[tg*3+1], wv*rel_s[e*3+1]);
      atomicAdd(&vel[tg*3+2], wv*rel_s[e*3+2]);
    }
  }
}

// ---------------- node update (MFMA) + fused next-layer operand production ----------------
__global__ __launch_bounds__(256) void k_node(
    const float* __restrict__ h, float* __restrict__ agg,
    const short* __restrict__ W1p, const float* __restrict__ b1,
    const short* __restrict__ W2p, const float* __restrict__ b2,
    const float* __restrict__ g, const float* __restrict__ bb_,
    float* __restrict__ h_out,
    int produce,                                   // 0 none, 1 Ptgt, 2 Ptgt+Psrc
    const float* __restrict__ temb,
    const short* __restrict__ W1bcN, const float* __restrict__ mb1N,
    const short* __restrict__ W1aN,
    short* __restrict__ Ptgt, short* __restrict__ PsrcQ)
{
  __shared__ __align__(16) short A[32*264];   // u bf16 str264; later r f32 str132
  __shared__ __align__(16) short B[32*136];   // hid bf16 str136
  __shared__ __align__(16) short S[32*264];   // [h_new | temb] bf16 str264 (production)
  float* r = (float*)A;
  int t = threadIdx.x;
  int n0 = blockIdx.x * 32;

  { // stage u = [h|agg] bf16, zero agg; stage temb -> S cols 128..255
    int row = t >> 3, l = t & 7;
    const float4* hr = (const float4*)(h + (size_t)(n0+row)*128);
    float4*       ar = (float4*)(agg + (size_t)(n0+row)*128);
    const float4* te = (const float4*)(temb + (size_t)(n0+row)*128);
    short* o = A + row*264;
    short* so = S + row*264 + 128;
    float4 z = make_float4(0.f,0.f,0.f,0.f);
    #pragma unroll
    for (int i = 0; i < 4; i++){
      int k4 = l + 8*i;
      float4 a = hr[k4];
      o[k4*4+0]=f2bf(a.x); o[k4*4+1]=f2bf(a.y); o[k4*4+2]=f2bf(a.z); o[k4*4+3]=f2bf(a.w);
      float4 b = ar[k4];
      o[128 + k4*4+0]=f2bf(b.x); o[128 + k4*4+1]=f2bf(b.y);
      o[128 + k4*4+2]=f2bf(b.z); o[128 + k4*4+3]=f2bf(b.w);
      ar[k4] = z;
      if (produce){
        float4 c = te[k4];
        so[k4*4+0]=f2bf(c.x); so[k4*4+1]=f2bf(c.y);
        so[k4*4+2]=f2bf(c.z); so[k4*4+3]=f2bf(c.w);
      }
    }
  }
  __syncthreads();

  int lane = t & 63, w = t >> 6;
  int mrow = lane & 15, quad = lane >> 4;

  // GEMM_A: (32x256)@(256x128)
  float4v accA[2][2];
  #pragma unroll
  for (int nti = 0; nti < 2; nti++){
    int nt = w*2 + nti;
    #pragma unroll
    for (int mt = 0; mt < 2; mt++){
      float4v acc = {0.f,0.f,0.f,0.f};
      const short8* Ab = (const short8*)(A + (mt*16 + mrow)*264 + quad*8);
      const short8* Bb = (const short8*)(W1p + (size_t)nt*8*512 + lane*8);
      #pragma unroll
      for (int kk = 0; kk < 8; kk++)
        acc = __builtin_amdgcn_mfma_f32_16x16x32_bf16(Ab[kk*4], Bb[kk*64], acc, 0, 0, 0);
      accA[nti][mt] = acc;
    }
  }
  __syncthreads();

  #pragma unroll
  for (int nti = 0; nti < 2; nti++){
    int n = (w*2 + nti)*16 + mrow;
    float b1n = b1[n];
    #pragma unroll
    for (int mt = 0; mt < 2; mt++){
      #pragma unroll
      for (int rr = 0; rr < 4; rr++){
        int e = mt*16 + quad*4 + rr;
        B[e*136 + n] = f2bf(silu_f(accA[nti][mt][rr] + b1n));
      }
    }
  }
  __syncthreads();

  // GEMM_B: (32x128)@(128x128) -> residual -> r
  #pragma unroll
  for (int nti = 0; nti < 2; nti++){
    int nt = w*2 + nti;
    #pragma unroll
    for (int mt = 0; mt < 2; mt++){
      float4v acc = {0.f,0.f,0.f,0.f};
      const short8* Ab = (const short8*)(B + (mt*16 + mrow)*136 + quad*8);
      const short8* Bb = (const short8*)(W2p + (size_t)nt*4*512 + lane*8);
      #pragma unroll
      for (int kk = 0; kk < 4; kk++)
        acc = __builtin_amdgcn_mfma_f32_16x16x32_bf16(Ab[kk*4], Bb[kk*64], acc, 0, 0, 0);
      int n = nt*16 + mrow;
      float b2n = b2[n];
      #pragma unroll
      for (int rr = 0; rr < 4; rr++){
        int e = mt*16 + quad*4 + rr;
        r[e*132 + n] = h[(size_t)(n0+e)*128 + n] + acc[rr] + b2n;
      }
    }
  }
  __syncthreads();

  // LayerNorm -> h_out global + S cols 0..127 (bf16)
  {
    int lane2 = t & 63, wid = t >> 6;
    #pragma unroll
    for (int nn = 0; nn < 8; nn++){
      int row = wid*8 + nn;
      float a = r[row*132 + lane2], bv = r[row*132 + lane2 + 64];
      float s = a + bv, ss = a*a + bv*bv;
      #pragma unroll
      for (int off = 1; off < 64; off <<= 1){
        s  += __shfl_xor(s, off);
        ss += __shfl_xor(ss, off);
      }
      float mean = s * (1.f/128.f);
      float var  = ss * (1.f/128.f) - mean*mean;
      float rstd = rsqrtf(var + 1e-5f);
      float v0 = (a  - mean)*rstd*g[lane2]      + bb_[lane2];
      float v1 = (bv - mean)*rstd*g[lane2 + 64] + bb_[lane2 + 64];
      float* ho = h_out + (size_t)(n0+row)*128;
      ho[lane2]      = v0;
      ho[lane2 + 64] = v1;
      S[row*264 + lane2]      = f2bf(v0);
      S[row*264 + lane2 + 64] = f2bf(v1);
    }
  }
  if (!produce) return;
  __syncthreads();

  // ---- produce Ptgt_{j+1} = [h_new|temb] @ W1bcN + mb1N ----
  #pragma unroll
  for (int nti = 0; nti < 4; nti++){
    int nt = w*4 + nti;
    #pragma unroll
    for (int mt = 0; mt < 2; mt++){
      float4v acc = {0.f,0.f,0.f,0.f};
      const short8* Ab = (const short8*)(S + (mt*16 + mrow)*264 + quad*8);
      const short8* Bb = (const short8*)(W1bcN + (size_t)nt*8*512 + lane*8);
      #pragma unroll
      for (int kk = 0; kk < 8; kk++)
        acc = __builtin_amdgcn_mfma_f32_16x16x32_bf16(Ab[kk*4], Bb[kk*64], acc, 0, 0, 0);
      int n = nt*16 + mrow;
      float bv = mb1N[n];
      #pragma unroll
      for (int rr = 0; rr < 4; rr++)
        Ptgt[(size_t)(n0 + mt*16 + quad*4 + rr)*256 + n] = f2bf(acc[rr] + bv);
    }
  }

  // ---- produce Psrc_{j+1} = h_new @ W1aN (QQ next layer only) ----
  if (produce == 2){
    #pragma unroll
    for (int nti = 0; nti < 4; nti++){
      int nt = w*4 + nti;
      #pragma unroll
      for (int mt = 0; mt < 2; mt++){
        float4v acc = {0.f,0.f,0.f,0.f};
        const short8* Ab = (const short8*)(S + (mt*16 + mrow)*264 + quad*8);
        const short8* Bb = (const short8*)(W1aN + (size_t)nt*4*512 + lane*8);
        #pragma unroll
        for (int kk = 0; kk < 4; kk++)
          acc = __builtin_amdgcn_mfma_f32_16x16x32_bf16(Ab[kk*4], Bb[kk*64], acc, 0, 0, 0);
        int n = nt*16 + mrow;
        #pragma unroll
        for (int rr = 0; rr < 4; rr++)
          PsrcQ[(size_t)(n0 + mt*16 + quad*4 + rr)*256 + n] = f2bf(acc[rr]);
      }
    }
  }
}

// ---------------- output ----------------
__global__ __launch_bounds__(128) void k_out(
    const float* __restrict__ h, const float* __restrict__ vel,
    const float* __restrict__ W1, const float* __restrict__ b1,
    const float* __restrict__ W2, const float* __restrict__ b2,
    float* __restrict__ out)
{
  __shared__ float sh[128];
  __shared__ float spart[2];
  int n = blockIdx.x, t = threadIdx.x;
  sh[t] = h[(size_t)n*128 + t];
  __syncthreads();
  float acc = b1[t];
  for (int k = 0; k < 128; k++) acc += sh[k] * W1[k*128 + t];
  float p = silu_f(acc) * W2[t];
  #pragma unroll
  for (int off = 32; off; off >>= 1) p += __shfl_down(p, off);
  if ((t & 63) == 0) spart[t >> 6] = p;
  __syncthreads();
  if (t < 3){
    float scale = spart[0] + spart[1] + b2[0];
    out[n*3 + t] = vel[n*3 + t] * scale;
  }
}

extern "C" void kernel_launch(void* const* d_in, const int* in_sizes, int n_in,
                              void* d_out, int out_size, void* d_ws, size_t ws_size,
                              hipStream_t stream)
{
  const float* x_t       = (const float*)d_in[0];
  const float* t_query   = (const float*)d_in[1];
  const float* atom_pos  = (const float*)d_in[2];
  const float* atom_feat = (const float*)d_in[3];
  const int*   e_aq_s = (const int*)d_in[4];
  const int*   e_aq_t = (const int*)d_in[5];
  const int*   e_qq_s = (const int*)d_in[6];
  const int*   e_qq_t = (const int*)d_in[7];
  const float* apW  = (const float*)d_in[8];
  const float* apb  = (const float*)d_in[9];
  const float* tW1  = (const float*)d_in[10];
  const float* tb1  = (const float*)d_in[11];
  const float* tW2  = (const float*)d_in[12];
  const float* tb2  = (const float*)d_in[13];
  const float* qiW1 = (const float*)d_in[14];
  const float* qib1 = (const float*)d_in[15];
  const float* qiW2 = (const float*)d_in[16];
  const float* qib2 = (const float*)d_in[17];
  const float* mW1  = (const float*)d_in[18];
  const float* mb1  = (const float*)d_in[19];
  const float* mW2  = (const float*)d_in[20];
  const float* mb2  = (const float*)d_in[21];
  const float* cW1  = (const float*)d_in[22];
  const float* cb1  = (const float*)d_in[23];
  const float* cW2  = (const float*)d_in[24];
  const float* cb2  = (const float*)d_in[25];
  const float* nW1  = (const float*)d_in[26];
  const float* nb1  = (const float*)d_in[27];
  const float* nW2  = (const float*)d_in[28];
  const float* nb2  = (const float*)d_in[29];
  const float* lng  = (const float*)d_in[30];
  const float* lnb  = (const float*)d_in[31];
  const float* voW1 = (const float*)d_in[32];
  const float* vob1 = (const float*)d_in[33];
  const float* voW2 = (const float*)d_in[34];
  const float* vob2 = (const float*)d_in[35];
  float* out = (float*)d_out;

  float* ws     = (float*)d_ws;
  float* h_atom = ws;                        // 65536
  float* temb   = h_atom + 65536;            // 2097152
  float* hA     = temb + 2097152;
  float* hB     = hA + 2097152;
  float* agg    = hB + 2097152;              // contiguous with vel
  float* vel    = agg + 2097152;             // 49152
  short* W1ap   = (short*)(vel + 49152);     // 262144
  short* W1bcp  = W1ap + 262144;             // 524288
  short* W2p    = W1bcp + 524288;            // 262144
  short* W3p    = W2p + 262144;              // 65536
  short* nW1p   = W3p + 65536;               // 262144
  short* nW2p   = nW1p + 262144;             // 131072
  short* tW1p   = nW2p + 131072;             // 65536
  short* tW2p   = tW1p + 65536;              // 65536
  short* PsrcQ  = tW2p + 65536;              // 4194304
  short* Ptgt   = PsrcQ + 4194304;           // 4194304
  short* psrc_aq= Ptgt + 4194304;            // 4*131072 = 524288
  int*   hist_a = (int*)(psrc_aq + 524288);  // 16384 (contiguous with hist_q)
  int*   hist_q = hist_a + 16384;            // 16384
  int2*  desc_a = (int2*)(hist_q + 16384);   // EAQ
  int2*  desc_q = desc_a + EAQ;              // EQQ

  // ---- sort both edge sets ----
  hipMemsetAsync(hist_a, 0, 2*16384*sizeof(int), stream);
  k_hist2<<<EQQ/256, 256, 0, stream>>>(e_aq_t, e_qq_t, hist_a, hist_q);
  k_scan2<<<2, 256, 0, stream>>>(hist_a, hist_q);
  k_place2<<<EQQ/256, 256, 0, stream>>>(e_aq_s, e_aq_t, e_qq_s, e_qq_t,
                                        hist_a, hist_q, desc_a, desc_q);

  // ---- all weight packing in one launch ----
  k_packall<<<6400, 256, 0, stream>>>(mW1, mW2, cW1, nW1, nW2, tW1, tW2,
      W1ap, W1bcp, W2p, W3p, nW1p, nW2p, tW1p, tW2p);

  // zero agg + vel (contiguous)
  hipMemsetAsync(agg, 0, (size_t)(NQT*128 + NQT*3)*sizeof(float), stream);
  k_hatom<<<NAT, 128, 0, stream>>>(atom_feat, apW, apb, h_atom);
  k_temb<<<NQT/32, 256, 0, stream>>>(t_query, tW1p, tb1, tW2p, tb2, temb);
  k_hinit<<<NQT, 128, 0, stream>>>(x_t, atom_pos, qiW1, qib1, qiW2, qib2, hA);

  // initial operands: Ptgt for layer 0 + Psrc for all 4 AQ layers
  k_pre0<<<NQT/64 + 32, 256, 0, stream>>>(hA, temb, mb1, W1bcp, h_atom, W1ap,
                                          Ptgt, psrc_aq);

  float* hc = hA; float* hn = hB;
  for (int j = 0; j < 8; j++){
    int half = j & 1;                       // 0 = AQ, 1 = QQ
    const int2* dsc = half ? desc_q : desc_a;
    int E = half ? EQQ : EAQ;
    const short* psrc = half ? PsrcQ : (psrc_aq + (size_t)(j >> 1)*131072);

    k_edge<<<E/32, 256, 0, stream>>>(psrc, Ptgt,
        half ? x_t : atom_pos, x_t, dsc,
        mW1 + (size_t)j*385*256 + 65536,
        W2p + (size_t)j*32768, mb2 + (size_t)j*128,
        W3p + (size_t)j*8192,  cb1 + (size_t)j*64,
        cW2 + (size_t)j*64,    cb2 + (size_t)j,
        agg, vel);

    int jn = (j < 7) ? (j + 1) : 7;         // next-layer weights (dummy when produce=0)
    int produce = (j == 7) ? 0 : ((half == 0) ? 2 : 1);
    k_node<<<NQT/32, 256, 0, stream>>>(hc, agg,
        nW1p + (size_t)j*32768, nb1 + (size_t)j*128,
        nW2p + (size_t)j*16384, nb2 + (size_t)j*128,
        lng + (size_t)j*128,    lnb + (size_t)j*128, hn,
        produce, temb,
        W1bcp + (size_t)jn*65536, mb1 + (size_t)jn*256,
        W1ap + (size_t)jn*32768,
        Ptgt, PsrcQ);
    float* tmp = hc; hc = hn; hn = tmp;
  }
  k_out<<<NQT, 128, 0, stream>>>(hc, vel, voW1, vob1, voW2, vob2, out);
}